// Round 1
// baseline (1683.756 us; speedup 1.0000x reference)
//
#include <hip/hip_runtime.h>
#include <math.h>

#define N_  4096
#define D_  128
#define B_  2
#define CL_ 64
#define CH_ 192

// ---------------------------------------------------------------------------
// Unified flash-attention kernel.
// Q,K,V laid out (d, N) per batch (column n = spatial position).
// query position in N-space: seq_off + (q0+q)*pos_stride, seq_off = by*seq_mult
// key   position in N-space: seq_off + k*pos_stride
// Writes/accumulates  M[c][pos] += wdir[widx] * O[q][c]  (store_mode=1 -> store)
// diag=1 applies count weights cnt[k]=64-|k-63| (the collapsed diag attention).
// ---------------------------------------------------------------------------
struct AttnParams {
  const float *Qh, *Ql, *Kh, *Kl, *Vh, *Vl;
  float *ML, *MH;
  const float *alpha;
  int seq_mult, pos_stride, Lk, Lq, widx, store_mode, diag;
};

__global__ __launch_bounds__(256, 1)
void attn_kernel(AttnParams p) {
  __shared__ __align__(16) float Qs[128][68];
  __shared__ __align__(16) float Ks[128][68];
  __shared__ __align__(16) float Vs[128][68];
  __shared__ __align__(16) float Ps[64][68];

  const int tid = threadIdx.x;
  const int tx = tid & 15;        // 4 keys (S phase) / 8 channels (O phase)
  const int ty = tid >> 4;        // 4 queries
  const int b = blockIdx.z >> 1, pair = blockIdx.z & 1;

  // pair 0: out_ll path (Q from hf-stream, K/V from ll-stream); pair 1: reverse
  const float* Q = pair ? p.Ql : p.Qh;
  const float* K = pair ? p.Kh : p.Kl;
  const float* V = pair ? p.Vh : p.Vl;
  float* M = pair ? p.MH : p.ML;
  const size_t boff = (size_t)b * D_ * N_;
  Q += boff; K += boff; V += boff; M += boff;

  // wdir = softmax(alpha); select widx
  float a0 = p.alpha[0], a1 = p.alpha[1], a2 = p.alpha[2], a3 = p.alpha[3];
  float am = fmaxf(fmaxf(a0, a1), fmaxf(a2, a3));
  float e0 = __expf(a0-am), e1 = __expf(a1-am), e2 = __expf(a2-am), e3 = __expf(a3-am);
  float wsel = (p.widx==0 ? e0 : p.widx==1 ? e1 : p.widx==2 ? e2 : e3) / (e0+e1+e2+e3);

  const int seq_off = blockIdx.y * p.seq_mult;
  const int q0 = blockIdx.x << 6;
  const float scl = 0.08838834764831845f;  // 128^-0.5

  // load Q tile: Qs[c][q]
  for (int r = 0; r < 32; ++r) {
    int flat = (r << 8) + tid;
    int c = flat >> 6, qq = flat & 63;
    int qi = q0 + qq; qi = qi < p.Lq ? qi : p.Lq - 1;   // clamp (write guarded later)
    Qs[c][qq] = Q[(size_t)c * N_ + seq_off + (size_t)qi * p.pos_stride];
  }

  float o[4][8];
  #pragma unroll
  for (int i = 0; i < 4; ++i)
    #pragma unroll
    for (int u = 0; u < 8; ++u) o[i][u] = 0.f;
  float m_run[4] = {-INFINITY, -INFINITY, -INFINITY, -INFINITY};
  float l_run[4] = {0.f, 0.f, 0.f, 0.f};

  const int ntiles = (p.Lk + 63) >> 6;
  for (int kt = 0; kt < ntiles; ++kt) {
    const int kbase = kt << 6;
    __syncthreads();   // prev O-phase done (Ks/Vs/Ps reuse); Q tile visible
    for (int r = 0; r < 32; ++r) {
      int flat = (r << 8) + tid;
      int c = flat >> 6, kk = flat & 63;
      int ki = kbase + kk;
      Ks[c][kk] = (ki < p.Lk) ? K[(size_t)c*N_ + seq_off + (size_t)ki*p.pos_stride] : 0.f;
    }
    for (int r = 0; r < 32; ++r) {
      int flat = (r << 8) + tid;
      int c = flat >> 6, kk = flat & 63;
      int ki = kbase + kk;
      Vs[c][kk] = (ki < p.Lk) ? V[(size_t)c*N_ + seq_off + (size_t)ki*p.pos_stride] : 0.f;
    }
    __syncthreads();

    // ---- S = Q^T K  (thread: 4q x 4k) ----
    float s[4][4];
    #pragma unroll
    for (int i = 0; i < 4; ++i)
      #pragma unroll
      for (int j = 0; j < 4; ++j) s[i][j] = 0.f;

    #pragma unroll 4
    for (int c = 0; c < 128; ++c) {
      float4 qv = *(const float4*)&Qs[c][ty << 2];
      float4 kv = *(const float4*)&Ks[c][tx << 2];
      s[0][0] += qv.x*kv.x; s[0][1] += qv.x*kv.y; s[0][2] += qv.x*kv.z; s[0][3] += qv.x*kv.w;
      s[1][0] += qv.y*kv.x; s[1][1] += qv.y*kv.y; s[1][2] += qv.y*kv.z; s[1][3] += qv.y*kv.w;
      s[2][0] += qv.z*kv.x; s[2][1] += qv.z*kv.y; s[2][2] += qv.z*kv.z; s[2][3] += qv.z*kv.w;
      s[3][0] += qv.w*kv.x; s[3][1] += qv.w*kv.y; s[3][2] += qv.w*kv.z; s[3][3] += qv.w*kv.w;
    }

    // per-key weights (mask OOB; diag count weights)
    float cw[4];
    #pragma unroll
    for (int j = 0; j < 4; ++j) {
      int kg = kbase + (tx << 2) + j;
      float v = (kg < p.Lk) ? 1.f : 0.f;
      if (p.diag) {
        int dd = kg - 63; dd = dd < 0 ? -dd : dd;
        v = (kg < p.Lk) ? (float)(64 - dd) : 0.f;
      }
      cw[j] = v;
    }

    // ---- online softmax (rows shared by 16-lane tx-groups) ----
    #pragma unroll
    for (int i = 0; i < 4; ++i) {
      float mt = -INFINITY;
      #pragma unroll
      for (int j = 0; j < 4; ++j) { s[i][j] *= scl; mt = fmaxf(mt, s[i][j]); }
      #pragma unroll
      for (int off = 1; off < 16; off <<= 1) mt = fmaxf(mt, __shfl_xor(mt, off, 64));
      float mn = fmaxf(m_run[i], mt);
      float corr = __expf(m_run[i] - mn);   // exp(-inf)=0 on first tile
      m_run[i] = mn;
      float pj0 = cw[0] * __expf(s[i][0] - mn);
      float pj1 = cw[1] * __expf(s[i][1] - mn);
      float pj2 = cw[2] * __expf(s[i][2] - mn);
      float pj3 = cw[3] * __expf(s[i][3] - mn);
      float rs = pj0 + pj1 + pj2 + pj3;
      #pragma unroll
      for (int off = 1; off < 16; off <<= 1) rs += __shfl_xor(rs, off, 64);
      l_run[i] = l_run[i] * corr + rs;
      #pragma unroll
      for (int u = 0; u < 8; ++u) o[i][u] *= corr;
      *(float4*)&Ps[(ty<<2)+i][tx<<2] = make_float4(pj0, pj1, pj2, pj3);
    }
    __syncthreads();

    // ---- O += P @ V^T  (thread: 4q x 8c, c = tx + 16u) ----
    #pragma unroll 2
    for (int k4 = 0; k4 < 16; ++k4) {
      float4 p0 = *(const float4*)&Ps[(ty<<2)+0][k4<<2];
      float4 p1 = *(const float4*)&Ps[(ty<<2)+1][k4<<2];
      float4 p2 = *(const float4*)&Ps[(ty<<2)+2][k4<<2];
      float4 p3 = *(const float4*)&Ps[(ty<<2)+3][k4<<2];
      #pragma unroll
      for (int u = 0; u < 8; ++u) {
        float4 v4 = *(const float4*)&Vs[tx + (u<<4)][k4<<2];
        o[0][u] += p0.x*v4.x + p0.y*v4.y + p0.z*v4.z + p0.w*v4.w;
        o[1][u] += p1.x*v4.x + p1.y*v4.y + p1.z*v4.z + p1.w*v4.w;
        o[2][u] += p2.x*v4.x + p2.y*v4.y + p2.z*v4.z + p2.w*v4.w;
        o[3][u] += p3.x*v4.x + p3.y*v4.y + p3.z*v4.z + p3.w*v4.w;
      }
    }
  }

  // ---- epilogue: normalize, stage transposed into Qs (reuse), coalesced out ----
  __syncthreads();
  #pragma unroll
  for (int i = 0; i < 4; ++i) {
    float sc = wsel / l_run[i];
    #pragma unroll
    for (int u = 0; u < 8; ++u)
      Qs[tx + (u<<4)][(ty<<2)+i] = o[i][u] * sc;
  }
  __syncthreads();
  for (int r = 0; r < 32; ++r) {
    int flat = (r << 8) + tid;
    int c = flat >> 6, qq = flat & 63;
    int qi = q0 + qq;
    if (qi < p.Lq) {
      size_t addr = (size_t)c*N_ + seq_off + (size_t)qi*p.pos_stride;
      float v = Qs[c][qq];
      if (p.store_mode) M[addr] = v; else M[addr] += v;
    }
  }
}

// ---------------------------------------------------------------------------
// Tiled GEMM: Y[o][n] = sum_c Wm[o][c]*X[c][n] (+bias[o]) (+res[o][n])
// 64x64 block tile, 256 threads, 4x4 per thread. N fixed = 4096.
// ---------------------------------------------------------------------------
struct GemmParams {
  const float *Wm, *X, *res, *bias;
  float *Y;
  int O, K;
  long long sx, sy, sres;   // per-batch element strides
};

__global__ __launch_bounds__(256, 2)
void gemm_kernel(GemmParams g) {
  __shared__ __align__(16) float Wt[32][68];  // [c][o]
  __shared__ __align__(16) float Xt[32][68];  // [c][n]
  const int tid = threadIdx.x;
  const int tx = tid & 15, ty = tid >> 4;
  const int n0 = blockIdx.x << 6;
  const int ot0 = blockIdx.y << 6;
  const int b = blockIdx.z;

  const float* X = g.X + (long long)b * g.sx;
  float* Y = g.Y + (long long)b * g.sy;
  const float* res = g.res ? (g.res + (long long)b * g.sres) : nullptr;

  float acc[4][4];
  #pragma unroll
  for (int i = 0; i < 4; ++i)
    #pragma unroll
    for (int j = 0; j < 4; ++j) acc[i][j] = 0.f;

  for (int c0 = 0; c0 < g.K; c0 += 32) {
    __syncthreads();
    #pragma unroll
    for (int r = 0; r < 8; ++r) {
      int flat = (r << 8) + tid;
      int oo = flat >> 5, c = flat & 31;
      Wt[c][oo] = g.Wm[(size_t)(ot0 + oo) * g.K + c0 + c];
    }
    #pragma unroll
    for (int r = 0; r < 8; ++r) {
      int flat = (r << 8) + tid;
      int c = flat >> 6, nn = flat & 63;
      Xt[c][nn] = X[(size_t)(c0 + c) * N_ + n0 + nn];
    }
    __syncthreads();
    #pragma unroll 8
    for (int c = 0; c < 32; ++c) {
      float4 wv = *(const float4*)&Wt[c][ty << 2];
      float4 xv = *(const float4*)&Xt[c][tx << 2];
      acc[0][0] += wv.x*xv.x; acc[0][1] += wv.x*xv.y; acc[0][2] += wv.x*xv.z; acc[0][3] += wv.x*xv.w;
      acc[1][0] += wv.y*xv.x; acc[1][1] += wv.y*xv.y; acc[1][2] += wv.y*xv.z; acc[1][3] += wv.y*xv.w;
      acc[2][0] += wv.z*xv.x; acc[2][1] += wv.z*xv.y; acc[2][2] += wv.z*xv.z; acc[2][3] += wv.z*xv.w;
      acc[3][0] += wv.w*xv.x; acc[3][1] += wv.w*xv.y; acc[3][2] += wv.w*xv.z; acc[3][3] += wv.w*xv.w;
    }
  }

  #pragma unroll
  for (int i = 0; i < 4; ++i) {
    int oo = ot0 + (ty << 2) + i;
    float bv = g.bias ? g.bias[oo] : 0.f;
    float4 outv = make_float4(acc[i][0]+bv, acc[i][1]+bv, acc[i][2]+bv, acc[i][3]+bv);
    if (res) {
      float4 r4 = *(const float4*)&res[(size_t)oo*N_ + n0 + (tx<<2)];
      outv.x += r4.x; outv.y += r4.y; outv.z += r4.z; outv.w += r4.w;
    }
    *(float4*)&Y[(size_t)oo*N_ + n0 + (tx<<2)] = outv;
  }
}

// ---------------------------------------------------------------------------
extern "C" void kernel_launch(void* const* d_in, const int* in_sizes, int n_in,
                              void* d_out, int out_size, void* d_ws, size_t ws_size,
                              hipStream_t stream) {
  (void)in_sizes; (void)n_in; (void)out_size; (void)ws_size;
  const float* ll  = (const float*)d_in[0];
  const float* hf  = (const float*)d_in[1];
  const float* Wqh = (const float*)d_in[2];
  const float* Wkh = (const float*)d_in[3];
  const float* Wvh = (const float*)d_in[4];
  const float* Wql = (const float*)d_in[5];
  const float* Wkl = (const float*)d_in[6];
  const float* Wvl = (const float*)d_in[7];
  const float* Wph = (const float*)d_in[8];
  const float* bph = (const float*)d_in[9];
  const float* Wpl = (const float*)d_in[10];
  const float* bpl = (const float*)d_in[11];
  const float* Wah = (const float*)d_in[12];
  const float* bah = (const float*)d_in[13];
  const float* Wal = (const float*)d_in[14];
  const float* bal = (const float*)d_in[15];
  const float* alpha = (const float*)d_in[16];

  // workspace layout (floats): 6 QKV + ML + MH + Ul + Uh  = ~42 MB
  float* ws = (float*)d_ws;
  const size_t BDN = (size_t)B_ * D_ * N_;   // 1048576
  float* Qh = ws;
  float* Kh = Qh + BDN;
  float* Vh = Kh + BDN;
  float* Ql = Vh + BDN;
  float* Kl = Ql + BDN;
  float* Vl = Kl + BDN;
  float* ML = Vl + BDN;
  float* MH = ML + BDN;
  float* Ul = MH + BDN;
  float* Uh = Ul + (size_t)B_ * CL_ * N_;

  dim3 blk(256, 1, 1);
  const long long sLL = (long long)CL_ * N_;
  const long long sHF = (long long)CH_ * N_;
  const long long sDN = (long long)D_  * N_;

  auto gemm = [&](const float* W, const float* X, const float* res, const float* bias,
                  float* Y, int O, int K, long long sx, long long sy, long long sres) {
    GemmParams g{W, X, res, bias, Y, O, K, sx, sy, sres};
    gemm_kernel<<<dim3(N_/64, O/64, B_), blk, 0, stream>>>(g);
  };
  auto attn = [&](int gx, int gy, int seq_mult, int pos_stride, int Lk, int Lq,
                  int widx, int store_mode, int diag) {
    AttnParams p{Qh, Ql, Kh, Kl, Vh, Vl, ML, MH, alpha,
                 seq_mult, pos_stride, Lk, Lq, widx, store_mode, diag};
    attn_kernel<<<dim3(gx, gy, 2*B_), blk, 0, stream>>>(p);
  };

  // QKV projections
  gemm(Wqh, hf, nullptr, nullptr, Qh, D_, CH_, sHF, sDN, 0);
  gemm(Wkh, hf, nullptr, nullptr, Kh, D_, CH_, sHF, sDN, 0);
  gemm(Wvh, hf, nullptr, nullptr, Vh, D_, CH_, sHF, sDN, 0);
  gemm(Wql, ll, nullptr, nullptr, Ql, D_, CL_, sLL, sDN, 0);
  gemm(Wkl, ll, nullptr, nullptr, Kl, D_, CL_, sLL, sDN, 0);
  gemm(Wvl, ll, nullptr, nullptr, Vl, D_, CL_, sLL, sDN, 0);

  // attention terms accumulated into ML/MH with wdir weights
  attn(64, 1, 0, 1, N_, N_, 3, 1, 0);    // global (store, w[3])
  attn(1, 64, 64, 1, 64, 64, 0, 0, 0);   // rows   (add,   w[0])
  attn(1, 64, 1, 64, 64, 64, 1, 0, 0);   // cols   (add,   w[1])
  attn(2, 1, 0, 1, 127, 127, 2, 0, 1);   // diag   (add,   w[2], count weights)

  // U = x + Wp @ M + bp    (wdir sums to 1 -> single bias application)
  gemm(Wpl, ML, ll, bpl, Ul, CL_, D_, sDN, sLL, sLL);
  gemm(Wph, MH, hf, bph, Uh, CH_, D_, sDN, sHF, sHF);

  // final: out = Wa @ U + ba
  float* out = (float*)d_out;
  gemm(Wal, Ul, nullptr, bal, out,                          CL_, CL_, sLL, sLL, 0);
  gemm(Wah, Uh, nullptr, bah, out + (size_t)B_ * CL_ * N_,  CH_, CH_, sHF, sHF, 0);
}

// Round 3
// 425.166 us; speedup vs baseline: 3.9602x; 3.9602x over previous
//
#include <hip/hip_runtime.h>
#include <math.h>

#define N_  4096
#define D_  128
#define B_  2
#define CL_ 64
#define CH_ 192

typedef __attribute__((ext_vector_type(8))) short short8;
typedef __attribute__((ext_vector_type(4))) float f32x4;

#if __has_builtin(__builtin_amdgcn_exp2f)
#define EXP2(x) __builtin_amdgcn_exp2f(x)
#else
#define EXP2(x) exp2f(x)
#endif

__device__ __forceinline__ short f2bf(float x) {
  union { float f; unsigned u; } v; v.f = x;
  unsigned r = v.u + 0x7FFFu + ((v.u >> 16) & 1u);
  return (short)(r >> 16);
}

typedef __attribute__((address_space(1))) const void gv_t;
typedef __attribute__((address_space(3))) void sv_t;
__device__ __forceinline__ void gl_lds16(const void* g, void* l) {
  __builtin_amdgcn_global_load_lds((gv_t*)g, (sv_t*)l, 16, 0, 0);
}

// ---------------------------------------------------------------------------
// Convert f32 (d,N) -> bf16 (N,d), rows 256B, XOR-swizzled within row
// (element d ^= (n&7)<<3), optional scale (Q gets scl*log2e folded in).
// ---------------------------------------------------------------------------
__global__ __launch_bounds__(256)
void convT_kernel(const float* __restrict__ src, short* __restrict__ dst, float scale) {
  __shared__ float Ls[128][65];
  const int tid = threadIdx.x;
  const int n0 = blockIdx.x * 64;
  const int b = blockIdx.y;
  src += (size_t)b * D_ * N_;
  dst += (size_t)b * N_ * D_;
  for (int it = 0; it < 32; ++it) {
    int flat = it*256 + tid;
    int c = flat >> 6, nn = flat & 63;
    Ls[c][nn] = src[(size_t)c*N_ + n0 + nn];
  }
  __syncthreads();
  for (int it = 0; it < 4; ++it) {
    int chunk = it*256 + tid;            // 0..1023
    int nn = chunk >> 4, ch = chunk & 15;
    int chs = ch ^ (nn & 7);
    short8 v;
    #pragma unroll
    for (int j = 0; j < 8; ++j) v[j] = f2bf(Ls[ch*8 + j][nn] * scale);
    *(short8*)(dst + (size_t)(n0 + nn)*D_ + chs*8) = v;
  }
}

// ---------------------------------------------------------------------------
// Convert f32 (d,N) -> bf16 (d,N), XOR-swizzled within each 64-col block
// (element (k&63) ^= (c&7)<<3).
// ---------------------------------------------------------------------------
__global__ __launch_bounds__(256)
void convN_kernel(const float* __restrict__ src, short* __restrict__ dst) {
  const int b = blockIdx.y;
  src += (size_t)b * D_ * N_;
  dst += (size_t)b * D_ * N_;
  int t = blockIdx.x * 256 + threadIdx.x;   // 0..65535 : one 8-elem chunk each
  int c = t >> 9;                            // 512 chunks per row
  int kc = t & 511;
  int k0 = kc * 8;
  int chs = (kc & 7) ^ (c & 7);
  const float* s = src + (size_t)c*N_ + k0;
  short8 v;
  #pragma unroll
  for (int j = 0; j < 8; ++j) v[j] = f2bf(s[j]);
  *(short8*)(dst + (size_t)c*N_ + (k0 & ~63) + chs*8) = v;
}

// ---------------------------------------------------------------------------
// Global (N x N) cross attention, bf16 MFMA flash kernel.
// 256 blocks: xcd-grouped so each XCD's L2 caches one (b,pair)'s K/V.
// Block: 64 queries, 4 waves x 16 q. KB=64 keys/iter, dbuf K/V.
// LDS layout (byte offsets into smem):
//   Q: 0..16K   K: 16K + cur*16K   V: 48K + cur*16K   P: 80K..88K
// ---------------------------------------------------------------------------
#define QOFF 0
#define KOFF 16384
#define VOFF 49152
#define POFF 81920

struct GlobalAttnParams {
  const short *Qhb, *Qlb, *Khb, *Klb, *Vhb, *Vlb;
  float *ML, *MH;
  const float* alpha;
};

__global__ __launch_bounds__(256, 1)
void attn_gl_kernel(GlobalAttnParams p) {
  __shared__ __align__(16) char smem[90112];
  const int tid = threadIdx.x;
  const int lane = tid & 63, wid = tid >> 6;
  const int m = lane & 15, hi = lane >> 4;

  // block swizzle: xcd = bx&7 (2 XCDs per (b,pair) -> K/V fits 4MB L2)
  const int bx = blockIdx.x;
  const int xcd = bx & 7, sub = bx >> 3;
  const int pz = xcd >> 1;
  const int b = pz >> 1, pair = pz & 1;
  const int q0 = ((xcd & 1) * 32 + sub) * 64;

  const short* Qb = (pair ? p.Qlb : p.Qhb) + (size_t)b * N_ * D_;
  const short* Kb = (pair ? p.Khb : p.Klb) + (size_t)b * N_ * D_;
  const short* Vb = (pair ? p.Vhb : p.Vlb) + (size_t)b * D_ * N_;
  float* M = (pair ? p.MH : p.ML) + (size_t)b * D_ * N_;

  float a0 = p.alpha[0], a1 = p.alpha[1], a2 = p.alpha[2], a3 = p.alpha[3];
  float am = fmaxf(fmaxf(a0,a1), fmaxf(a2,a3));
  float e0 = __expf(a0-am), e1 = __expf(a1-am), e2 = __expf(a2-am), e3 = __expf(a3-am);
  const float wsel = e3 / (e0+e1+e2+e3);

  auto stageC = [&](int ldsoff, const short* g) {            // 16KB contiguous
    #pragma unroll
    for (int i = 0; i < 4; ++i) {
      int chunk = wid*4 + i;
      gl_lds16(g + chunk*512 + lane*8, smem + ldsoff + chunk*1024);
    }
  };
  auto stageV = [&](int ldsoff, const short* g) {            // 128 rows x 128B, stride N_
    #pragma unroll
    for (int i = 0; i < 4; ++i) {
      int chunk = wid*4 + i;
      gl_lds16(g + (size_t)(chunk*8 + (lane>>3))*N_ + (lane&7)*8, smem + ldsoff + chunk*1024);
    }
  };

  stageC(QOFF, Qb + (size_t)q0 * D_);
  stageC(KOFF, Kb);
  stageV(VOFF, Vb);
  __syncthreads();   // compiler drains vmcnt(0) before s_barrier

  // hoist Q fragments (A-operand, rows = lane&15)
  const int qrow = wid*16 + m;
  short8 qf[4];
  #pragma unroll
  for (int cs = 0; cs < 4; ++cs)
    qf[cs] = *(const short8*)(smem + QOFF + qrow*256 + ((cs*64 + hi*16) ^ ((qrow&7)<<4)));

  f32x4 oacc[8];
  #pragma unroll
  for (int i = 0; i < 8; ++i) oacc[i] = (f32x4){0.f,0.f,0.f,0.f};
  float m_run[4] = {-INFINITY,-INFINITY,-INFINITY,-INFINITY};
  float l_run[4] = {0.f,0.f,0.f,0.f};

  const int NT = N_ / 64;
  int cur = 0;
  for (int kt = 0; kt < NT; ++kt) {
    if (kt + 1 < NT) {                       // prefetch next tile (T3 2-phase)
      stageC(KOFF + (cur^1)*16384, Kb + (size_t)(kt+1)*64*D_);
      stageV(VOFF + (cur^1)*16384, Vb + (kt+1)*64);
    }
    const char* Kcur = smem + KOFF + cur*16384;
    const char* Vcur = smem + VOFF + cur*16384;
    // ---- S = Q K^T  (4 kf frags of 16 keys) ----
    f32x4 sacc[4];
    #pragma unroll
    for (int kf = 0; kf < 4; ++kf) sacc[kf] = (f32x4){0.f,0.f,0.f,0.f};
    #pragma unroll
    for (int kf = 0; kf < 4; ++kf) {
      const int krow = kf*16 + m;
      const char* kr = Kcur + krow*256;
      #pragma unroll
      for (int cs = 0; cs < 4; ++cs) {
        short8 kfr = *(const short8*)(kr + ((cs*64 + hi*16) ^ ((krow&7)<<4)));
        sacc[kf] = __builtin_amdgcn_mfma_f32_16x16x32_bf16(qf[cs], kfr, sacc[kf], 0,0,0);
      }
    }
    // ---- online softmax (log2 domain; scl*log2e folded into Q) ----
    #pragma unroll
    for (int r = 0; r < 4; ++r) {
      float mt = fmaxf(fmaxf(sacc[0][r], sacc[1][r]), fmaxf(sacc[2][r], sacc[3][r]));
      mt = fmaxf(mt, __shfl_xor(mt, 1));
      mt = fmaxf(mt, __shfl_xor(mt, 2));
      mt = fmaxf(mt, __shfl_xor(mt, 4));
      mt = fmaxf(mt, __shfl_xor(mt, 8));
      float mn = fmaxf(m_run[r], mt);
      float corr = EXP2(m_run[r] - mn);      // exp2(-inf)=0 on first tile
      m_run[r] = mn;
      const int qr = wid*16 + hi*4 + r;      // C/D row (m89-verified layout)
      char* prow = smem + POFF + qr*128;
      float psum = 0.f;
      #pragma unroll
      for (int kf = 0; kf < 4; ++kf) {
        float pv = EXP2(sacc[kf][r] - mn);
        psum += pv;
        int kcol = (kf*16 + m)*2;
        *(short*)(prow + (kcol ^ ((qr&7)<<4))) = f2bf(pv);
      }
      psum += __shfl_xor(psum, 1);
      psum += __shfl_xor(psum, 2);
      psum += __shfl_xor(psum, 4);
      psum += __shfl_xor(psum, 8);
      l_run[r] = l_run[r]*corr + psum;
      #pragma unroll
      for (int cf = 0; cf < 8; ++cf) oacc[cf][r] *= corr;
    }
    // ---- O += P V^T  (P strip is per-wave private; DS ops in-order) ----
    #pragma unroll
    for (int ks = 0; ks < 2; ++ks) {
      short8 pa = *(const short8*)(smem + POFF + qrow*128 + ((ks*64 + hi*16) ^ ((qrow&7)<<4)));
      #pragma unroll
      for (int cf = 0; cf < 8; ++cf) {
        const int crow = cf*16 + m;
        short8 vf = *(const short8*)(Vcur + crow*128 + ((ks*64 + hi*16) ^ ((crow&7)<<4)));
        oacc[cf] = __builtin_amdgcn_mfma_f32_16x16x32_bf16(pa, vf, oacc[cf], 0,0,0);
      }
    }
    __syncthreads();   // vmcnt(0)-drains prefetch; protects buffer reuse
    cur ^= 1;
  }

  // ---- epilogue: scale, transpose via LDS, coalesced f32 store ----
  float inv[4];
  #pragma unroll
  for (int r = 0; r < 4; ++r) inv[r] = wsel / l_run[r];
  float* Os = (float*)smem;   // [128][66] = 33792B, overlays Q/K region
  #pragma unroll
  for (int cf = 0; cf < 8; ++cf)
    #pragma unroll
    for (int r = 0; r < 4; ++r)
      Os[(cf*16 + m)*66 + wid*16 + hi*4 + r] = oacc[cf][r] * inv[r];
  __syncthreads();
  for (int it = 0; it < 32; ++it) {
    int flat = it*256 + tid;
    int c = flat >> 6, qq = flat & 63;
    M[(size_t)c*N_ + q0 + qq] = Os[c*66 + qq];   // store (global term is first)
  }
}

// ---------------------------------------------------------------------------
// f32 flash-attention kernel (axial row/col + diag paths only now).
// ---------------------------------------------------------------------------
struct AttnParams {
  const float *Qh, *Ql, *Kh, *Kl, *Vh, *Vl;
  float *ML, *MH;
  const float *alpha;
  int seq_mult, pos_stride, Lk, Lq, widx, store_mode, diag;
};

__global__ __launch_bounds__(256, 1)
void attn_kernel(AttnParams p) {
  __shared__ __align__(16) float Qs[128][68];
  __shared__ __align__(16) float Ks[128][68];
  __shared__ __align__(16) float Vs[128][68];
  __shared__ __align__(16) float Ps[64][68];

  const int tid = threadIdx.x;
  const int tx = tid & 15;
  const int ty = tid >> 4;
  const int b = blockIdx.z >> 1, pair = blockIdx.z & 1;

  const float* Q = pair ? p.Ql : p.Qh;
  const float* K = pair ? p.Kh : p.Kl;
  const float* V = pair ? p.Vh : p.Vl;
  float* M = pair ? p.MH : p.ML;
  const size_t boff = (size_t)b * D_ * N_;
  Q += boff; K += boff; V += boff; M += boff;

  float a0 = p.alpha[0], a1 = p.alpha[1], a2 = p.alpha[2], a3 = p.alpha[3];
  float am = fmaxf(fmaxf(a0, a1), fmaxf(a2, a3));
  float e0 = __expf(a0-am), e1 = __expf(a1-am), e2 = __expf(a2-am), e3 = __expf(a3-am);
  float wsel = (p.widx==0 ? e0 : p.widx==1 ? e1 : p.widx==2 ? e2 : e3) / (e0+e1+e2+e3);

  const int seq_off = blockIdx.y * p.seq_mult;
  const int q0 = blockIdx.x << 6;
  const float scl = 0.08838834764831845f;

  for (int r = 0; r < 32; ++r) {
    int flat = (r << 8) + tid;
    int c = flat >> 6, qq = flat & 63;
    int qi = q0 + qq; qi = qi < p.Lq ? qi : p.Lq - 1;
    Qs[c][qq] = Q[(size_t)c * N_ + seq_off + (size_t)qi * p.pos_stride];
  }

  float o[4][8];
  #pragma unroll
  for (int i = 0; i < 4; ++i)
    #pragma unroll
    for (int u = 0; u < 8; ++u) o[i][u] = 0.f;
  float m_run[4] = {-INFINITY, -INFINITY, -INFINITY, -INFINITY};
  float l_run[4] = {0.f, 0.f, 0.f, 0.f};

  const int ntiles = (p.Lk + 63) >> 6;
  for (int kt = 0; kt < ntiles; ++kt) {
    const int kbase = kt << 6;
    __syncthreads();
    for (int r = 0; r < 32; ++r) {
      int flat = (r << 8) + tid;
      int c = flat >> 6, kk = flat & 63;
      int ki = kbase + kk;
      Ks[c][kk] = (ki < p.Lk) ? K[(size_t)c*N_ + seq_off + (size_t)ki*p.pos_stride] : 0.f;
    }
    for (int r = 0; r < 32; ++r) {
      int flat = (r << 8) + tid;
      int c = flat >> 6, kk = flat & 63;
      int ki = kbase + kk;
      Vs[c][kk] = (ki < p.Lk) ? V[(size_t)c*N_ + seq_off + (size_t)ki*p.pos_stride] : 0.f;
    }
    __syncthreads();

    float s[4][4];
    #pragma unroll
    for (int i = 0; i < 4; ++i)
      #pragma unroll
      for (int j = 0; j < 4; ++j) s[i][j] = 0.f;

    #pragma unroll 4
    for (int c = 0; c < 128; ++c) {
      float4 qv = *(const float4*)&Qs[c][ty << 2];
      float4 kv = *(const float4*)&Ks[c][tx << 2];
      s[0][0] += qv.x*kv.x; s[0][1] += qv.x*kv.y; s[0][2] += qv.x*kv.z; s[0][3] += qv.x*kv.w;
      s[1][0] += qv.y*kv.x; s[1][1] += qv.y*kv.y; s[1][2] += qv.y*kv.z; s[1][3] += qv.y*kv.w;
      s[2][0] += qv.z*kv.x; s[2][1] += qv.z*kv.y; s[2][2] += qv.z*kv.z; s[2][3] += qv.z*kv.w;
      s[3][0] += qv.w*kv.x; s[3][1] += qv.w*kv.y; s[3][2] += qv.w*kv.z; s[3][3] += qv.w*kv.w;
    }

    float cw[4];
    #pragma unroll
    for (int j = 0; j < 4; ++j) {
      int kg = kbase + (tx << 2) + j;
      float v = (kg < p.Lk) ? 1.f : 0.f;
      if (p.diag) {
        int dd = kg - 63; dd = dd < 0 ? -dd : dd;
        v = (kg < p.Lk) ? (float)(64 - dd) : 0.f;
      }
      cw[j] = v;
    }

    #pragma unroll
    for (int i = 0; i < 4; ++i) {
      float mt = -INFINITY;
      #pragma unroll
      for (int j = 0; j < 4; ++j) { s[i][j] *= scl; mt = fmaxf(mt, s[i][j]); }
      #pragma unroll
      for (int off = 1; off < 16; off <<= 1) mt = fmaxf(mt, __shfl_xor(mt, off, 64));
      float mn = fmaxf(m_run[i], mt);
      float corr = __expf(m_run[i] - mn);
      m_run[i] = mn;
      float pj0 = cw[0] * __expf(s[i][0] - mn);
      float pj1 = cw[1] * __expf(s[i][1] - mn);
      float pj2 = cw[2] * __expf(s[i][2] - mn);
      float pj3 = cw[3] * __expf(s[i][3] - mn);
      float rs = pj0 + pj1 + pj2 + pj3;
      #pragma unroll
      for (int off = 1; off < 16; off <<= 1) rs += __shfl_xor(rs, off, 64);
      l_run[i] = l_run[i] * corr + rs;
      #pragma unroll
      for (int u = 0; u < 8; ++u) o[i][u] *= corr;
      *(float4*)&Ps[(ty<<2)+i][tx<<2] = make_float4(pj0, pj1, pj2, pj3);
    }
    __syncthreads();

    #pragma unroll 2
    for (int k4 = 0; k4 < 16; ++k4) {
      float4 p0 = *(const float4*)&Ps[(ty<<2)+0][k4<<2];
      float4 p1 = *(const float4*)&Ps[(ty<<2)+1][k4<<2];
      float4 p2 = *(const float4*)&Ps[(ty<<2)+2][k4<<2];
      float4 p3 = *(const float4*)&Ps[(ty<<2)+3][k4<<2];
      #pragma unroll
      for (int u = 0; u < 8; ++u) {
        float4 v4 = *(const float4*)&Vs[tx + (u<<4)][k4<<2];
        o[0][u] += p0.x*v4.x + p0.y*v4.y + p0.z*v4.z + p0.w*v4.w;
        o[1][u] += p1.x*v4.x + p1.y*v4.y + p1.z*v4.z + p1.w*v4.w;
        o[2][u] += p2.x*v4.x + p2.y*v4.y + p2.z*v4.z + p2.w*v4.w;
        o[3][u] += p3.x*v4.x + p3.y*v4.y + p3.z*v4.z + p3.w*v4.w;
      }
    }
  }

  __syncthreads();
  #pragma unroll
  for (int i = 0; i < 4; ++i) {
    float sc = wsel / l_run[i];
    #pragma unroll
    for (int u = 0; u < 8; ++u)
      Qs[tx + (u<<4)][(ty<<2)+i] = o[i][u] * sc;
  }
  __syncthreads();
  for (int r = 0; r < 32; ++r) {
    int flat = (r << 8) + tid;
    int c = flat >> 6, qq = flat & 63;
    int qi = q0 + qq;
    if (qi < p.Lq) {
      size_t addr = (size_t)c*N_ + seq_off + (size_t)qi*p.pos_stride;
      float v = Qs[c][qq];
      if (p.store_mode) M[addr] = v; else M[addr] += v;
    }
  }
}

// ---------------------------------------------------------------------------
// Tiled GEMM: Y[o][n] = sum_c Wm[o][c]*X[c][n] (+bias[o]) (+res[o][n])
// ---------------------------------------------------------------------------
struct GemmParams {
  const float *Wm, *X, *res, *bias;
  float *Y;
  int O, K;
  long long sx, sy, sres;
};

__global__ __launch_bounds__(256, 2)
void gemm_kernel(GemmParams g) {
  __shared__ __align__(16) float Wt[32][68];
  __shared__ __align__(16) float Xt[32][68];
  const int tid = threadIdx.x;
  const int tx = tid & 15, ty = tid >> 4;
  const int n0 = blockIdx.x << 6;
  const int ot0 = blockIdx.y << 6;
  const int b = blockIdx.z;

  const float* X = g.X + (long long)b * g.sx;
  float* Y = g.Y + (long long)b * g.sy;
  const float* res = g.res ? (g.res + (long long)b * g.sres) : nullptr;

  float acc[4][4];
  #pragma unroll
  for (int i = 0; i < 4; ++i)
    #pragma unroll
    for (int j = 0; j < 4; ++j) acc[i][j] = 0.f;

  for (int c0 = 0; c0 < g.K; c0 += 32) {
    __syncthreads();
    #pragma unroll
    for (int r = 0; r < 8; ++r) {
      int flat = (r << 8) + tid;
      int oo = flat >> 5, c = flat & 31;
      Wt[c][oo] = g.Wm[(size_t)(ot0 + oo) * g.K + c0 + c];
    }
    #pragma unroll
    for (int r = 0; r < 8; ++r) {
      int flat = (r << 8) + tid;
      int c = flat >> 6, nn = flat & 63;
      Xt[c][nn] = X[(size_t)(c0 + c) * N_ + n0 + nn];
    }
    __syncthreads();
    #pragma unroll 8
    for (int c = 0; c < 32; ++c) {
      float4 wv = *(const float4*)&Wt[c][ty << 2];
      float4 xv = *(const float4*)&Xt[c][tx << 2];
      acc[0][0] += wv.x*xv.x; acc[0][1] += wv.x*xv.y; acc[0][2] += wv.x*xv.z; acc[0][3] += wv.x*xv.w;
      acc[1][0] += wv.y*xv.x; acc[1][1] += wv.y*xv.y; acc[1][2] += wv.y*xv.z; acc[1][3] += wv.y*xv.w;
      acc[2][0] += wv.z*xv.x; acc[2][1] += wv.z*xv.y; acc[2][2] += wv.z*xv.z; acc[2][3] += wv.z*xv.w;
      acc[3][0] += wv.w*xv.x; acc[3][1] += wv.w*xv.y; acc[3][2] += wv.w*xv.z; acc[3][3] += wv.w*xv.w;
    }
  }

  #pragma unroll
  for (int i = 0; i < 4; ++i) {
    int oo = ot0 + (ty << 2) + i;
    float bv = g.bias ? g.bias[oo] : 0.f;
    float4 outv = make_float4(acc[i][0]+bv, acc[i][1]+bv, acc[i][2]+bv, acc[i][3]+bv);
    if (res) {
      float4 r4 = *(const float4*)&res[(size_t)oo*N_ + n0 + (tx<<2)];
      outv.x += r4.x; outv.y += r4.y; outv.z += r4.z; outv.w += r4.w;
    }
    *(float4*)&Y[(size_t)oo*N_ + n0 + (tx<<2)] = outv;
  }
}

// ---------------------------------------------------------------------------
extern "C" void kernel_launch(void* const* d_in, const int* in_sizes, int n_in,
                              void* d_out, int out_size, void* d_ws, size_t ws_size,
                              hipStream_t stream) {
  (void)in_sizes; (void)n_in; (void)out_size; (void)ws_size;
  const float* ll  = (const float*)d_in[0];
  const float* hf  = (const float*)d_in[1];
  const float* Wqh = (const float*)d_in[2];
  const float* Wkh = (const float*)d_in[3];
  const float* Wvh = (const float*)d_in[4];
  const float* Wql = (const float*)d_in[5];
  const float* Wkl = (const float*)d_in[6];
  const float* Wvl = (const float*)d_in[7];
  const float* Wph = (const float*)d_in[8];
  const float* bph = (const float*)d_in[9];
  const float* Wpl = (const float*)d_in[10];
  const float* bpl = (const float*)d_in[11];
  const float* Wah = (const float*)d_in[12];
  const float* bah = (const float*)d_in[13];
  const float* Wal = (const float*)d_in[14];
  const float* bal = (const float*)d_in[15];
  const float* alpha = (const float*)d_in[16];

  float* ws = (float*)d_ws;
  const size_t BDN = (size_t)B_ * D_ * N_;   // 1048576
  float* Qh = ws;
  float* Kh = Qh + BDN;
  float* Vh = Kh + BDN;
  float* Ql = Vh + BDN;
  float* Kl = Ql + BDN;
  float* Vl = Kl + BDN;
  float* ML = Vl + BDN;
  float* MH = ML + BDN;
  float* Ul = MH + BDN;
  float* Uh = Ul + (size_t)B_ * CL_ * N_;
  short* Qhb = (short*)(Uh + (size_t)B_ * CH_ * N_);
  short* Qlb = Qhb + BDN;
  short* Khb = Qlb + BDN;
  short* Klb = Khb + BDN;
  short* Vhb = Klb + BDN;
  short* Vlb = Vhb + BDN;

  dim3 blk(256, 1, 1);
  const long long sLL = (long long)CL_ * N_;
  const long long sHF = (long long)CH_ * N_;
  const long long sDN = (long long)D_  * N_;

  auto gemm = [&](const float* W, const float* X, const float* res, const float* bias,
                  float* Y, int O, int K, long long sx, long long sy, long long sres) {
    GemmParams g{W, X, res, bias, Y, O, K, sx, sy, sres};
    gemm_kernel<<<dim3(N_/64, O/64, B_), blk, 0, stream>>>(g);
  };
  auto attn = [&](int gx, int gy, int seq_mult, int pos_stride, int Lk, int Lq,
                  int widx, int store_mode, int diag) {
    AttnParams p{Qh, Ql, Kh, Kl, Vh, Vl, ML, MH, alpha,
                 seq_mult, pos_stride, Lk, Lq, widx, store_mode, diag};
    attn_kernel<<<dim3(gx, gy, 2*B_), blk, 0, stream>>>(p);
  };

  // QKV projections (f32)
  gemm(Wqh, hf, nullptr, nullptr, Qh, D_, CH_, sHF, sDN, 0);
  gemm(Wkh, hf, nullptr, nullptr, Kh, D_, CH_, sHF, sDN, 0);
  gemm(Wvh, hf, nullptr, nullptr, Vh, D_, CH_, sHF, sDN, 0);
  gemm(Wql, ll, nullptr, nullptr, Ql, D_, CL_, sLL, sDN, 0);
  gemm(Wkl, ll, nullptr, nullptr, Kl, D_, CL_, sLL, sDN, 0);
  gemm(Wvl, ll, nullptr, nullptr, Vl, D_, CL_, sLL, sDN, 0);

  // bf16 swizzled copies for the MFMA global-attention kernel
  const float qscale = (float)(0.08838834764831845 * 1.4426950408889634);
  convT_kernel<<<dim3(N_/64, B_), blk, 0, stream>>>(Qh, Qhb, qscale);
  convT_kernel<<<dim3(N_/64, B_), blk, 0, stream>>>(Ql, Qlb, qscale);
  convT_kernel<<<dim3(N_/64, B_), blk, 0, stream>>>(Kh, Khb, 1.0f);
  convT_kernel<<<dim3(N_/64, B_), blk, 0, stream>>>(Kl, Klb, 1.0f);
  convN_kernel<<<dim3(256, B_), blk, 0, stream>>>(Vh, Vhb);
  convN_kernel<<<dim3(256, B_), blk, 0, stream>>>(Vl, Vlb);

  // global attention (MFMA, stores M with w[3])
  GlobalAttnParams gp{Qhb, Qlb, Khb, Klb, Vhb, Vlb, ML, MH, alpha};
  attn_gl_kernel<<<dim3(256, 1, 1), blk, 0, stream>>>(gp);

  // axial + diag (f32, accumulate)
  attn(1, 64, 64, 1, 64, 64, 0, 0, 0);   // rows   (w[0])
  attn(1, 64, 1, 64, 64, 64, 1, 0, 0);   // cols   (w[1])
  attn(2, 1, 0, 1, 127, 127, 2, 0, 1);   // diag   (w[2], count weights)

  // U = x + Wp @ M + bp
  gemm(Wpl, ML, ll, bpl, Ul, CL_, D_, sDN, sLL, sLL);
  gemm(Wph, MH, hf, bph, Uh, CH_, D_, sDN, sHF, sHF);

  // final: out = Wa @ U + ba
  float* out = (float*)d_out;
  gemm(Wal, Ul, nullptr, bal, out,                          CL_, CL_, sLL, sLL, 0);
  gemm(Wah, Uh, nullptr, bah, out + (size_t)B_ * CL_ * N_,  CH_, CH_, sHF, sHF, 0);
}

// Round 4
// 399.600 us; speedup vs baseline: 4.2136x; 1.0640x over previous
//
#include <hip/hip_runtime.h>
#include <math.h>

#define N_  4096
#define D_  128
#define B_  2
#define CL_ 64
#define CH_ 192

typedef __attribute__((ext_vector_type(8))) short short8;
typedef __attribute__((ext_vector_type(4))) short s16x4;
typedef __attribute__((ext_vector_type(4))) float f32x4;

#if __has_builtin(__builtin_amdgcn_exp2f)
#define EXP2(x) __builtin_amdgcn_exp2f(x)
#else
#define EXP2(x) exp2f(x)
#endif

__device__ __forceinline__ short f2bf(float x) {
  union { float f; unsigned u; } v; v.f = x;
  unsigned r = v.u + 0x7FFFu + ((v.u >> 16) & 1u);
  return (short)(r >> 16);
}

typedef __attribute__((address_space(1))) const void gv_t;
typedef __attribute__((address_space(3))) void sv_t;
__device__ __forceinline__ void gl_lds16(const void* g, void* l) {
  __builtin_amdgcn_global_load_lds((gv_t*)g, (sv_t*)l, 16, 0, 0);
}

// ---------------------------------------------------------------------------
// Fused QKV projection + bf16 swizzled-copy kernel.
// grid.y in 0..5: sel = y>>1 (0=Q,1=K,2=V), dhalf = y&1 (which 64 of D=128).
// Computes Y = W @ X (f32, [d][n]) and writes bf16 copies:
//   Q/K: [n][d] rows 256B, granule (d>>3) ^= (n&7); Q scaled by scl*log2e.
//   V:   [d][n], within each 64-col block granule ((n>>3)&7) ^= (d&7).
// ---------------------------------------------------------------------------
struct QkvParams {
  const float *X, *Wq, *Wk, *Wv;
  float *Yq, *Yk, *Yv;
  short *Qb, *Kb, *Vb;
  int C;
  float qscale;
};

__global__ __launch_bounds__(256, 2)
void qkv_kernel(QkvParams g) {
  __shared__ __align__(16) float Wt[32][68];
  __shared__ __align__(16) float Xt[32][68];
  const int tid = threadIdx.x;
  const int tx = tid & 15, ty = tid >> 4;
  const int n0 = blockIdx.x << 6;
  const int sel = blockIdx.y >> 1;
  const int dhalf = blockIdx.y & 1;
  const int ot0 = dhalf * 64;
  const int b = blockIdx.z;
  const int C = g.C;

  const float* X = g.X + (size_t)b * C * N_;
  const float* Wm = sel == 0 ? g.Wq : sel == 1 ? g.Wk : g.Wv;
  float* Yf = (sel == 0 ? g.Yq : sel == 1 ? g.Yk : g.Yv) + (size_t)b * D_ * N_;

  float acc[4][4];
  #pragma unroll
  for (int i = 0; i < 4; ++i)
    #pragma unroll
    for (int j = 0; j < 4; ++j) acc[i][j] = 0.f;

  for (int c0 = 0; c0 < C; c0 += 32) {
    __syncthreads();
    #pragma unroll
    for (int r = 0; r < 8; ++r) {
      int flat = (r << 8) + tid;
      int oo = flat >> 5, c = flat & 31;
      Wt[c][oo] = Wm[(size_t)(ot0 + oo) * C + c0 + c];
    }
    #pragma unroll
    for (int r = 0; r < 8; ++r) {
      int flat = (r << 8) + tid;
      int c = flat >> 6, nn = flat & 63;
      Xt[c][nn] = X[(size_t)(c0 + c) * N_ + n0 + nn];
    }
    __syncthreads();
    #pragma unroll 8
    for (int c = 0; c < 32; ++c) {
      float4 wv = *(const float4*)&Wt[c][ty << 2];
      float4 xv = *(const float4*)&Xt[c][tx << 2];
      acc[0][0] += wv.x*xv.x; acc[0][1] += wv.x*xv.y; acc[0][2] += wv.x*xv.z; acc[0][3] += wv.x*xv.w;
      acc[1][0] += wv.y*xv.x; acc[1][1] += wv.y*xv.y; acc[1][2] += wv.y*xv.z; acc[1][3] += wv.y*xv.w;
      acc[2][0] += wv.z*xv.x; acc[2][1] += wv.z*xv.y; acc[2][2] += wv.z*xv.z; acc[2][3] += wv.z*xv.w;
      acc[3][0] += wv.w*xv.x; acc[3][1] += wv.w*xv.y; acc[3][2] += wv.w*xv.z; acc[3][3] += wv.w*xv.w;
    }
  }

  // ---- f32 output [d][n] ----
  #pragma unroll
  for (int i = 0; i < 4; ++i) {
    int oo = ot0 + (ty << 2) + i;
    *(float4*)&Yf[(size_t)oo * N_ + n0 + (tx << 2)] =
        make_float4(acc[i][0], acc[i][1], acc[i][2], acc[i][3]);
  }

  // ---- bf16 swizzled outputs ----
  if (sel < 2) {               // Q/K: dst[n][d], granule (d>>3)^(n&7)
    short* Tb = (sel == 0 ? g.Qb : g.Kb) + (size_t)b * N_ * D_;
    float sc = sel == 0 ? g.qscale : 1.0f;
    #pragma unroll
    for (int j = 0; j < 4; ++j) {
      int n = n0 + (tx << 2) + j;
      int pg = (ty >> 1) ^ (n & 7);
      s16x4 v4 = { f2bf(acc[0][j]*sc), f2bf(acc[1][j]*sc),
                   f2bf(acc[2][j]*sc), f2bf(acc[3][j]*sc) };
      *(s16x4*)((char*)Tb + (size_t)n*256 + dhalf*128 + pg*16 + (ty & 1)*8) = v4;
    }
  } else {                     // V: dst[d][n], granule within 64-block ^(d&7)
    short* Vbp = g.Vb + (size_t)b * D_ * N_;
    #pragma unroll
    for (int i = 0; i < 4; ++i) {
      int d = ot0 + (ty << 2) + i;
      int pg = (tx >> 1) ^ (d & 7);
      s16x4 v4 = { f2bf(acc[i][0]), f2bf(acc[i][1]),
                   f2bf(acc[i][2]), f2bf(acc[i][3]) };
      *(s16x4*)((char*)Vbp + ((size_t)d*N_ + n0)*2 + pg*16 + (tx & 1)*8) = v4;
    }
  }
}

// ---------------------------------------------------------------------------
// Global (N x N) cross attention, bf16 MFMA flash kernel.
// 512 blocks x 128 threads (2 waves x 16 q = 32 q/block), 72KB LDS
// -> 2 blocks/CU so independent barrier groups overlap the vmcnt drain.
// LDS: P 0..4K (reuses Q 0..8K after hoist), K dbuf 8K..40K, V dbuf 40K..72K.
// ---------------------------------------------------------------------------
#define GKOFF 8192
#define GVOFF 40960

struct GlobalAttnParams {
  const short *Qhb, *Qlb, *Khb, *Klb, *Vhb, *Vlb;
  float *ML, *MH;
  const float* alpha;
};

__global__ __launch_bounds__(128, 1)
void attn_gl_kernel(GlobalAttnParams p) {
  __shared__ __align__(16) char smem[73728];
  const int tid = threadIdx.x;
  const int lane = tid & 63, wid = tid >> 6;
  const int m = lane & 15, hi = lane >> 4;

  // xcd grouping: 2 XCDs per (b,pair) -> K/V (2MB) fits the 4MB XCD L2
  const int bx = blockIdx.x;
  const int xcd = bx & 7, sub = bx >> 3;        // sub 0..63
  const int pz = xcd >> 1;
  const int b = pz >> 1, pair = pz & 1;
  const int q0 = ((xcd & 1) * 64 + sub) * 32;

  const short* Qb = (pair ? p.Qlb : p.Qhb) + (size_t)b * N_ * D_;
  const short* Kb = (pair ? p.Khb : p.Klb) + (size_t)b * N_ * D_;
  const short* Vb = (pair ? p.Vhb : p.Vlb) + (size_t)b * D_ * N_;
  float* M = (pair ? p.MH : p.ML) + (size_t)b * D_ * N_;

  float a0 = p.alpha[0], a1 = p.alpha[1], a2 = p.alpha[2], a3 = p.alpha[3];
  float am = fmaxf(fmaxf(a0,a1), fmaxf(a2,a3));
  float e0 = __expf(a0-am), e1 = __expf(a1-am), e2 = __expf(a2-am), e3 = __expf(a3-am);
  const float wsel = e3 / (e0+e1+e2+e3);

  auto stageK = [&](int off, const short* g) {   // 16KB contiguous (64 rows x 256B)
    #pragma unroll
    for (int i = 0; i < 8; ++i) {
      int chunk = wid*8 + i;
      gl_lds16(g + chunk*512 + lane*8, smem + off + chunk*1024);
    }
  };
  auto stageV = [&](int off, const short* g) {   // 128 rows x 128B, row stride N_
    #pragma unroll
    for (int i = 0; i < 8; ++i) {
      int chunk = wid*8 + i;
      gl_lds16(g + (size_t)(chunk*8 + (lane>>3))*N_ + (lane&7)*8, smem + off + chunk*1024);
    }
  };

  // stage Q (8KB at offset 0), K0, V0
  #pragma unroll
  for (int i = 0; i < 4; ++i) {
    int chunk = wid*4 + i;
    gl_lds16(Qb + (size_t)q0*D_ + chunk*512 + lane*8, smem + chunk*1024);
  }
  stageK(GKOFF, Kb);
  stageV(GVOFF, Vb);
  __syncthreads();

  // hoist Q fragments (A-operand rows = wave's 16 queries)
  const int qrow = wid*16 + m;
  short8 qf[4];
  #pragma unroll
  for (int cs = 0; cs < 4; ++cs)
    qf[cs] = *(const short8*)(smem + qrow*256 + ((cs*64 + hi*16) ^ ((qrow&7)<<4)));
  __syncthreads();   // Q region becomes the P strip after this point

  f32x4 oacc[8];
  #pragma unroll
  for (int i = 0; i < 8; ++i) oacc[i] = (f32x4){0.f,0.f,0.f,0.f};
  float m_run[4] = {-INFINITY,-INFINITY,-INFINITY,-INFINITY};
  float l_run[4] = {0.f,0.f,0.f,0.f};

  const int NT = N_ / 64;
  int cur = 0;
  for (int kt = 0; kt < NT; ++kt) {
    if (kt + 1 < NT) {                       // prefetch next tile
      stageK(GKOFF + (cur^1)*16384, Kb + (size_t)(kt+1)*64*D_);
      stageV(GVOFF + (cur^1)*16384, Vb + (kt+1)*64);
    }
    const char* Kcur = smem + GKOFF + cur*16384;
    const char* Vcur = smem + GVOFF + cur*16384;
    // ---- S = Q K^T ----
    f32x4 sacc[4];
    #pragma unroll
    for (int kf = 0; kf < 4; ++kf) sacc[kf] = (f32x4){0.f,0.f,0.f,0.f};
    #pragma unroll
    for (int kf = 0; kf < 4; ++kf) {
      const int krow = kf*16 + m;
      const char* kr = Kcur + krow*256;
      #pragma unroll
      for (int cs = 0; cs < 4; ++cs) {
        short8 kfr = *(const short8*)(kr + ((cs*64 + hi*16) ^ ((krow&7)<<4)));
        sacc[kf] = __builtin_amdgcn_mfma_f32_16x16x32_bf16(qf[cs], kfr, sacc[kf], 0,0,0);
      }
    }
    // ---- online softmax (log2 domain; scl*log2e folded into Q) ----
    #pragma unroll
    for (int r = 0; r < 4; ++r) {
      float mt = fmaxf(fmaxf(sacc[0][r], sacc[1][r]), fmaxf(sacc[2][r], sacc[3][r]));
      mt = fmaxf(mt, __shfl_xor(mt, 1));
      mt = fmaxf(mt, __shfl_xor(mt, 2));
      mt = fmaxf(mt, __shfl_xor(mt, 4));
      mt = fmaxf(mt, __shfl_xor(mt, 8));
      float mn = fmaxf(m_run[r], mt);
      float corr = EXP2(m_run[r] - mn);
      m_run[r] = mn;
      const int qr = wid*16 + hi*4 + r;      // C/D row (m89 layout)
      char* prow = smem + qr*128;
      float psum = 0.f;
      #pragma unroll
      for (int kf = 0; kf < 4; ++kf) {
        float pv = EXP2(sacc[kf][r] - mn);
        psum += pv;
        int kcol = (kf*16 + m)*2;
        *(short*)(prow + (kcol ^ ((qr&7)<<4))) = f2bf(pv);
      }
      psum += __shfl_xor(psum, 1);
      psum += __shfl_xor(psum, 2);
      psum += __shfl_xor(psum, 4);
      psum += __shfl_xor(psum, 8);
      l_run[r] = l_run[r]*corr + psum;
      #pragma unroll
      for (int cf = 0; cf < 8; ++cf) oacc[cf][r] *= corr;
    }
    // ---- O += P V^T (P strip per-wave private; DS in-order) ----
    #pragma unroll
    for (int ks = 0; ks < 2; ++ks) {
      short8 pa = *(const short8*)(smem + qrow*128 + ((ks*64 + hi*16) ^ ((qrow&7)<<4)));
      #pragma unroll
      for (int cf = 0; cf < 8; ++cf) {
        const int crow = cf*16 + m;
        short8 vf = *(const short8*)(Vcur + crow*128 + ((ks*64 + hi*16) ^ ((crow&7)<<4)));
        oacc[cf] = __builtin_amdgcn_mfma_f32_16x16x32_bf16(pa, vf, oacc[cf], 0,0,0);
      }
    }
    __syncthreads();   // drains prefetch vmcnt; protects buffer reuse
    cur ^= 1;
  }

  // ---- epilogue: scale, transpose via LDS, coalesced f32 store ----
  float inv[4];
  #pragma unroll
  for (int r = 0; r < 4; ++r) inv[r] = wsel / l_run[r];
  float* Os = (float*)smem;   // [128][33] = 16896B
  #pragma unroll
  for (int cf = 0; cf < 8; ++cf)
    #pragma unroll
    for (int r = 0; r < 4; ++r)
      Os[(cf*16 + m)*33 + wid*16 + hi*4 + r] = oacc[cf][r] * inv[r];
  __syncthreads();
  for (int it = 0; it < 32; ++it) {
    int flat = it*128 + tid;
    int c = flat >> 5, qq = flat & 31;
    M[(size_t)c*N_ + q0 + qq] = Os[c*33 + qq];   // store (global term first)
  }
}

// ---------------------------------------------------------------------------
// f32 flash-attention kernel (axial row/col + diag paths).
// ---------------------------------------------------------------------------
struct AttnParams {
  const float *Qh, *Ql, *Kh, *Kl, *Vh, *Vl;
  float *ML, *MH;
  const float *alpha;
  int seq_mult, pos_stride, Lk, Lq, widx, store_mode, diag;
};

__global__ __launch_bounds__(256, 1)
void attn_kernel(AttnParams p) {
  __shared__ __align__(16) float Qs[128][68];
  __shared__ __align__(16) float Ks[128][68];
  __shared__ __align__(16) float Vs[128][68];
  __shared__ __align__(16) float Ps[64][68];

  const int tid = threadIdx.x;
  const int tx = tid & 15;
  const int ty = tid >> 4;
  const int b = blockIdx.z >> 1, pair = blockIdx.z & 1;

  const float* Q = pair ? p.Ql : p.Qh;
  const float* K = pair ? p.Kh : p.Kl;
  const float* V = pair ? p.Vh : p.Vl;
  float* M = pair ? p.MH : p.ML;
  const size_t boff = (size_t)b * D_ * N_;
  Q += boff; K += boff; V += boff; M += boff;

  float a0 = p.alpha[0], a1 = p.alpha[1], a2 = p.alpha[2], a3 = p.alpha[3];
  float am = fmaxf(fmaxf(a0, a1), fmaxf(a2, a3));
  float e0 = __expf(a0-am), e1 = __expf(a1-am), e2 = __expf(a2-am), e3 = __expf(a3-am);
  float wsel = (p.widx==0 ? e0 : p.widx==1 ? e1 : p.widx==2 ? e2 : e3) / (e0+e1+e2+e3);

  const int seq_off = blockIdx.y * p.seq_mult;
  const int q0 = blockIdx.x << 6;
  const float scl = 0.08838834764831845f;

  for (int r = 0; r < 32; ++r) {
    int flat = (r << 8) + tid;
    int c = flat >> 6, qq = flat & 63;
    int qi = q0 + qq; qi = qi < p.Lq ? qi : p.Lq - 1;
    Qs[c][qq] = Q[(size_t)c * N_ + seq_off + (size_t)qi * p.pos_stride];
  }

  float o[4][8];
  #pragma unroll
  for (int i = 0; i < 4; ++i)
    #pragma unroll
    for (int u = 0; u < 8; ++u) o[i][u] = 0.f;
  float m_run[4] = {-INFINITY, -INFINITY, -INFINITY, -INFINITY};
  float l_run[4] = {0.f, 0.f, 0.f, 0.f};

  const int ntiles = (p.Lk + 63) >> 6;
  for (int kt = 0; kt < ntiles; ++kt) {
    const int kbase = kt << 6;
    __syncthreads();
    for (int r = 0; r < 32; ++r) {
      int flat = (r << 8) + tid;
      int c = flat >> 6, kk = flat & 63;
      int ki = kbase + kk;
      Ks[c][kk] = (ki < p.Lk) ? K[(size_t)c*N_ + seq_off + (size_t)ki*p.pos_stride] : 0.f;
    }
    for (int r = 0; r < 32; ++r) {
      int flat = (r << 8) + tid;
      int c = flat >> 6, kk = flat & 63;
      int ki = kbase + kk;
      Vs[c][kk] = (ki < p.Lk) ? V[(size_t)c*N_ + seq_off + (size_t)ki*p.pos_stride] : 0.f;
    }
    __syncthreads();

    float s[4][4];
    #pragma unroll
    for (int i = 0; i < 4; ++i)
      #pragma unroll
      for (int j = 0; j < 4; ++j) s[i][j] = 0.f;

    #pragma unroll 4
    for (int c = 0; c < 128; ++c) {
      float4 qv = *(const float4*)&Qs[c][ty << 2];
      float4 kv = *(const float4*)&Ks[c][tx << 2];
      s[0][0] += qv.x*kv.x; s[0][1] += qv.x*kv.y; s[0][2] += qv.x*kv.z; s[0][3] += qv.x*kv.w;
      s[1][0] += qv.y*kv.x; s[1][1] += qv.y*kv.y; s[1][2] += qv.y*kv.z; s[1][3] += qv.y*kv.w;
      s[2][0] += qv.z*kv.x; s[2][1] += qv.z*kv.y; s[2][2] += qv.z*kv.z; s[2][3] += qv.z*kv.w;
      s[3][0] += qv.w*kv.x; s[3][1] += qv.w*kv.y; s[3][2] += qv.w*kv.z; s[3][3] += qv.w*kv.w;
    }

    float cw[4];
    #pragma unroll
    for (int j = 0; j < 4; ++j) {
      int kg = kbase + (tx << 2) + j;
      float v = (kg < p.Lk) ? 1.f : 0.f;
      if (p.diag) {
        int dd = kg - 63; dd = dd < 0 ? -dd : dd;
        v = (kg < p.Lk) ? (float)(64 - dd) : 0.f;
      }
      cw[j] = v;
    }

    #pragma unroll
    for (int i = 0; i < 4; ++i) {
      float mt = -INFINITY;
      #pragma unroll
      for (int j = 0; j < 4; ++j) { s[i][j] *= scl; mt = fmaxf(mt, s[i][j]); }
      #pragma unroll
      for (int off = 1; off < 16; off <<= 1) mt = fmaxf(mt, __shfl_xor(mt, off, 64));
      float mn = fmaxf(m_run[i], mt);
      float corr = __expf(m_run[i] - mn);
      m_run[i] = mn;
      float pj0 = cw[0] * __expf(s[i][0] - mn);
      float pj1 = cw[1] * __expf(s[i][1] - mn);
      float pj2 = cw[2] * __expf(s[i][2] - mn);
      float pj3 = cw[3] * __expf(s[i][3] - mn);
      float rs = pj0 + pj1 + pj2 + pj3;
      #pragma unroll
      for (int off = 1; off < 16; off <<= 1) rs += __shfl_xor(rs, off, 64);
      l_run[i] = l_run[i] * corr + rs;
      #pragma unroll
      for (int u = 0; u < 8; ++u) o[i][u] *= corr;
      *(float4*)&Ps[(ty<<2)+i][tx<<2] = make_float4(pj0, pj1, pj2, pj3);
    }
    __syncthreads();

    #pragma unroll 2
    for (int k4 = 0; k4 < 16; ++k4) {
      float4 p0 = *(const float4*)&Ps[(ty<<2)+0][k4<<2];
      float4 p1 = *(const float4*)&Ps[(ty<<2)+1][k4<<2];
      float4 p2 = *(const float4*)&Ps[(ty<<2)+2][k4<<2];
      float4 p3 = *(const float4*)&Ps[(ty<<2)+3][k4<<2];
      #pragma unroll
      for (int u = 0; u < 8; ++u) {
        float4 v4 = *(const float4*)&Vs[tx + (u<<4)][k4<<2];
        o[0][u] += p0.x*v4.x + p0.y*v4.y + p0.z*v4.z + p0.w*v4.w;
        o[1][u] += p1.x*v4.x + p1.y*v4.y + p1.z*v4.z + p1.w*v4.w;
        o[2][u] += p2.x*v4.x + p2.y*v4.y + p2.z*v4.z + p2.w*v4.w;
        o[3][u] += p3.x*v4.x + p3.y*v4.y + p3.z*v4.z + p3.w*v4.w;
      }
    }
  }

  __syncthreads();
  #pragma unroll
  for (int i = 0; i < 4; ++i) {
    float sc = wsel / l_run[i];
    #pragma unroll
    for (int u = 0; u < 8; ++u)
      Qs[tx + (u<<4)][(ty<<2)+i] = o[i][u] * sc;
  }
  __syncthreads();
  for (int r = 0; r < 32; ++r) {
    int flat = (r << 8) + tid;
    int c = flat >> 6, qq = flat & 63;
    int qi = q0 + qq;
    if (qi < p.Lq) {
      size_t addr = (size_t)c*N_ + seq_off + (size_t)qi*p.pos_stride;
      float v = Qs[c][qq];
      if (p.store_mode) M[addr] = v; else M[addr] += v;
    }
  }
}

// ---------------------------------------------------------------------------
// Tiled GEMM: Y[o][n] = sum_c Wm[o][c]*X[c][n] (+bias[o]) (+res[o][n])
// ---------------------------------------------------------------------------
struct GemmParams {
  const float *Wm, *X, *res, *bias;
  float *Y;
  int O, K;
  long long sx, sy, sres;
};

__global__ __launch_bounds__(256, 2)
void gemm_kernel(GemmParams g) {
  __shared__ __align__(16) float Wt[32][68];
  __shared__ __align__(16) float Xt[32][68];
  const int tid = threadIdx.x;
  const int tx = tid & 15, ty = tid >> 4;
  const int n0 = blockIdx.x << 6;
  const int ot0 = blockIdx.y << 6;
  const int b = blockIdx.z;

  const float* X = g.X + (long long)b * g.sx;
  float* Y = g.Y + (long long)b * g.sy;
  const float* res = g.res ? (g.res + (long long)b * g.sres) : nullptr;

  float acc[4][4];
  #pragma unroll
  for (int i = 0; i < 4; ++i)
    #pragma unroll
    for (int j = 0; j < 4; ++j) acc[i][j] = 0.f;

  for (int c0 = 0; c0 < g.K; c0 += 32) {
    __syncthreads();
    #pragma unroll
    for (int r = 0; r < 8; ++r) {
      int flat = (r << 8) + tid;
      int oo = flat >> 5, c = flat & 31;
      Wt[c][oo] = g.Wm[(size_t)(ot0 + oo) * g.K + c0 + c];
    }
    #pragma unroll
    for (int r = 0; r < 8; ++r) {
      int flat = (r << 8) + tid;
      int c = flat >> 6, nn = flat & 63;
      Xt[c][nn] = X[(size_t)(c0 + c) * N_ + n0 + nn];
    }
    __syncthreads();
    #pragma unroll 8
    for (int c = 0; c < 32; ++c) {
      float4 wv = *(const float4*)&Wt[c][ty << 2];
      float4 xv = *(const float4*)&Xt[c][tx << 2];
      acc[0][0] += wv.x*xv.x; acc[0][1] += wv.x*xv.y; acc[0][2] += wv.x*xv.z; acc[0][3] += wv.x*xv.w;
      acc[1][0] += wv.y*xv.x; acc[1][1] += wv.y*xv.y; acc[1][2] += wv.y*xv.z; acc[1][3] += wv.y*xv.w;
      acc[2][0] += wv.z*xv.x; acc[2][1] += wv.z*xv.y; acc[2][2] += wv.z*xv.z; acc[2][3] += wv.z*xv.w;
      acc[3][0] += wv.w*xv.x; acc[3][1] += wv.w*xv.y; acc[3][2] += wv.w*xv.z; acc[3][3] += wv.w*xv.w;
    }
  }

  #pragma unroll
  for (int i = 0; i < 4; ++i) {
    int oo = ot0 + (ty << 2) + i;
    float bv = g.bias ? g.bias[oo] : 0.f;
    float4 outv = make_float4(acc[i][0]+bv, acc[i][1]+bv, acc[i][2]+bv, acc[i][3]+bv);
    if (res) {
      float4 r4 = *(const float4*)&res[(size_t)oo*N_ + n0 + (tx<<2)];
      outv.x += r4.x; outv.y += r4.y; outv.z += r4.z; outv.w += r4.w;
    }
    *(float4*)&Y[(size_t)oo*N_ + n0 + (tx<<2)] = outv;
  }
}

// ---------------------------------------------------------------------------
extern "C" void kernel_launch(void* const* d_in, const int* in_sizes, int n_in,
                              void* d_out, int out_size, void* d_ws, size_t ws_size,
                              hipStream_t stream) {
  (void)in_sizes; (void)n_in; (void)out_size; (void)ws_size;
  const float* ll  = (const float*)d_in[0];
  const float* hf  = (const float*)d_in[1];
  const float* Wqh = (const float*)d_in[2];
  const float* Wkh = (const float*)d_in[3];
  const float* Wvh = (const float*)d_in[4];
  const float* Wql = (const float*)d_in[5];
  const float* Wkl = (const float*)d_in[6];
  const float* Wvl = (const float*)d_in[7];
  const float* Wph = (const float*)d_in[8];
  const float* bph = (const float*)d_in[9];
  const float* Wpl = (const float*)d_in[10];
  const float* bpl = (const float*)d_in[11];
  const float* Wah = (const float*)d_in[12];
  const float* bah = (const float*)d_in[13];
  const float* Wal = (const float*)d_in[14];
  const float* bal = (const float*)d_in[15];
  const float* alpha = (const float*)d_in[16];

  float* ws = (float*)d_ws;
  const size_t BDN = (size_t)B_ * D_ * N_;   // 1048576
  float* Qh = ws;
  float* Kh = Qh + BDN;
  float* Vh = Kh + BDN;
  float* Ql = Vh + BDN;
  float* Kl = Ql + BDN;
  float* Vl = Kl + BDN;
  float* ML = Vl + BDN;
  float* MH = ML + BDN;
  float* Ul = MH + BDN;
  float* Uh = Ul + (size_t)B_ * CL_ * N_;
  short* Qhb = (short*)(Uh + (size_t)B_ * CH_ * N_);
  short* Qlb = Qhb + BDN;
  short* Khb = Qlb + BDN;
  short* Klb = Khb + BDN;
  short* Vhb = Klb + BDN;
  short* Vlb = Vhb + BDN;

  dim3 blk(256, 1, 1);
  const long long sLL = (long long)CL_ * N_;
  const long long sHF = (long long)CH_ * N_;
  const long long sDN = (long long)D_  * N_;
  const float qscale = (float)(0.08838834764831845 * 1.4426950408889634);

  // fused QKV projections + bf16 swizzled copies (one kernel per stream)
  {
    QkvParams qh{hf, Wqh, Wkh, Wvh, Qh, Kh, Vh, Qhb, Khb, Vhb, CH_, qscale};
    qkv_kernel<<<dim3(N_/64, 6, B_), blk, 0, stream>>>(qh);
    QkvParams ql{ll, Wql, Wkl, Wvl, Ql, Kl, Vl, Qlb, Klb, Vlb, CL_, qscale};
    qkv_kernel<<<dim3(N_/64, 6, B_), blk, 0, stream>>>(ql);
  }

  // global attention (MFMA, stores M with w[3])
  GlobalAttnParams gp{Qhb, Qlb, Khb, Klb, Vhb, Vlb, ML, MH, alpha};
  attn_gl_kernel<<<dim3(512, 1, 1), dim3(128,1,1), 0, stream>>>(gp);

  // axial + diag (f32, accumulate)
  auto attn = [&](int gx, int gy, int seq_mult, int pos_stride, int Lk, int Lq,
                  int widx, int store_mode, int diag) {
    AttnParams p{Qh, Ql, Kh, Kl, Vh, Vl, ML, MH, alpha,
                 seq_mult, pos_stride, Lk, Lq, widx, store_mode, diag};
    attn_kernel<<<dim3(gx, gy, 2*B_), blk, 0, stream>>>(p);
  };
  attn(1, 64, 64, 1, 64, 64, 0, 0, 0);   // rows   (w[0])
  attn(1, 64, 1, 64, 64, 64, 1, 0, 0);   // cols   (w[1])
  attn(2, 1, 0, 1, 127, 127, 2, 0, 1);   // diag   (w[2], count weights)

  auto gemm = [&](const float* W, const float* X, const float* res, const float* bias,
                  float* Y, int O, int K, long long sx, long long sy, long long sres) {
    GemmParams g{W, X, res, bias, Y, O, K, sx, sy, sres};
    gemm_kernel<<<dim3(N_/64, O/64, B_), blk, 0, stream>>>(g);
  };

  // U = x + Wp @ M + bp   (wdir sums to 1 -> single bias application)
  gemm(Wpl, ML, ll, bpl, Ul, CL_, D_, sDN, sLL, sLL);
  gemm(Wph, MH, hf, bph, Uh, CH_, D_, sDN, sHF, sHF);

  // final: out = Wa @ U + ba
  float* out = (float*)d_out;
  gemm(Wal, Ul, nullptr, bal, out,                          CL_, CL_, sLL, sLL, 0);
  gemm(Wah, Uh, nullptr, bah, out + (size_t)B_ * CL_ * N_,  CH_, CH_, sHF, sHF, 0);
}

// Round 5
// 363.313 us; speedup vs baseline: 4.6345x; 1.0999x over previous
//
#include <hip/hip_runtime.h>
#include <math.h>

#define N_  4096
#define D_  128
#define B_  2
#define CL_ 64
#define CH_ 192

typedef __attribute__((ext_vector_type(8))) short short8;
typedef __attribute__((ext_vector_type(4))) short s16x4;
typedef __attribute__((ext_vector_type(4))) float f32x4;

#if __has_builtin(__builtin_amdgcn_exp2f)
#define EXP2(x) __builtin_amdgcn_exp2f(x)
#else
#define EXP2(x) exp2f(x)
#endif

__device__ __forceinline__ short f2bf(float x) {
  union { float f; unsigned u; } v; v.f = x;
  unsigned r = v.u + 0x7FFFu + ((v.u >> 16) & 1u);
  return (short)(r >> 16);
}

typedef __attribute__((address_space(1))) const void gv_t;
typedef __attribute__((address_space(3))) void sv_t;
__device__ __forceinline__ void gl_lds16(const void* g, void* l) {
  __builtin_amdgcn_global_load_lds((gv_t*)g, (sv_t*)l, 16, 0, 0);
}

// ---------------------------------------------------------------------------
// Fused QKV projection + bf16 swizzled-copy kernel (unchanged from round 4).
// ---------------------------------------------------------------------------
struct QkvParams {
  const float *X, *Wq, *Wk, *Wv;
  float *Yq, *Yk, *Yv;
  short *Qb, *Kb, *Vb;
  int C;
  float qscale;
};

__global__ __launch_bounds__(256, 2)
void qkv_kernel(QkvParams g) {
  __shared__ __align__(16) float Wt[32][68];
  __shared__ __align__(16) float Xt[32][68];
  const int tid = threadIdx.x;
  const int tx = tid & 15, ty = tid >> 4;
  const int n0 = blockIdx.x << 6;
  const int sel = blockIdx.y >> 1;
  const int dhalf = blockIdx.y & 1;
  const int ot0 = dhalf * 64;
  const int b = blockIdx.z;
  const int C = g.C;

  const float* X = g.X + (size_t)b * C * N_;
  const float* Wm = sel == 0 ? g.Wq : sel == 1 ? g.Wk : g.Wv;
  float* Yf = (sel == 0 ? g.Yq : sel == 1 ? g.Yk : g.Yv) + (size_t)b * D_ * N_;

  float acc[4][4];
  #pragma unroll
  for (int i = 0; i < 4; ++i)
    #pragma unroll
    for (int j = 0; j < 4; ++j) acc[i][j] = 0.f;

  for (int c0 = 0; c0 < C; c0 += 32) {
    __syncthreads();
    #pragma unroll
    for (int r = 0; r < 8; ++r) {
      int flat = (r << 8) + tid;
      int oo = flat >> 5, c = flat & 31;
      Wt[c][oo] = Wm[(size_t)(ot0 + oo) * C + c0 + c];
    }
    #pragma unroll
    for (int r = 0; r < 8; ++r) {
      int flat = (r << 8) + tid;
      int c = flat >> 6, nn = flat & 63;
      Xt[c][nn] = X[(size_t)(c0 + c) * N_ + n0 + nn];
    }
    __syncthreads();
    #pragma unroll 8
    for (int c = 0; c < 32; ++c) {
      float4 wv = *(const float4*)&Wt[c][ty << 2];
      float4 xv = *(const float4*)&Xt[c][tx << 2];
      acc[0][0] += wv.x*xv.x; acc[0][1] += wv.x*xv.y; acc[0][2] += wv.x*xv.z; acc[0][3] += wv.x*xv.w;
      acc[1][0] += wv.y*xv.x; acc[1][1] += wv.y*xv.y; acc[1][2] += wv.y*xv.z; acc[1][3] += wv.y*xv.w;
      acc[2][0] += wv.z*xv.x; acc[2][1] += wv.z*xv.y; acc[2][2] += wv.z*xv.z; acc[2][3] += wv.z*xv.w;
      acc[3][0] += wv.w*xv.x; acc[3][1] += wv.w*xv.y; acc[3][2] += wv.w*xv.z; acc[3][3] += wv.w*xv.w;
    }
  }

  #pragma unroll
  for (int i = 0; i < 4; ++i) {
    int oo = ot0 + (ty << 2) + i;
    *(float4*)&Yf[(size_t)oo * N_ + n0 + (tx << 2)] =
        make_float4(acc[i][0], acc[i][1], acc[i][2], acc[i][3]);
  }

  if (sel < 2) {               // Q/K: dst[n][d], granule (d>>3)^(n&7)
    short* Tb = (sel == 0 ? g.Qb : g.Kb) + (size_t)b * N_ * D_;
    float sc = sel == 0 ? g.qscale : 1.0f;
    #pragma unroll
    for (int j = 0; j < 4; ++j) {
      int n = n0 + (tx << 2) + j;
      int pg = (ty >> 1) ^ (n & 7);
      s16x4 v4 = { f2bf(acc[0][j]*sc), f2bf(acc[1][j]*sc),
                   f2bf(acc[2][j]*sc), f2bf(acc[3][j]*sc) };
      *(s16x4*)((char*)Tb + (size_t)n*256 + dhalf*128 + pg*16 + (ty & 1)*8) = v4;
    }
  } else {                     // V: dst[d][n], granule within 64-block ^(d&7)
    short* Vbp = g.Vb + (size_t)b * D_ * N_;
    #pragma unroll
    for (int i = 0; i < 4; ++i) {
      int d = ot0 + (ty << 2) + i;
      int pg = (tx >> 1) ^ (d & 7);
      s16x4 v4 = { f2bf(acc[i][0]), f2bf(acc[i][1]),
                   f2bf(acc[i][2]), f2bf(acc[i][3]) };
      *(s16x4*)((char*)Vbp + ((size_t)d*N_ + n0)*2 + pg*16 + (tx & 1)*8) = v4;
    }
  }
}

// ---------------------------------------------------------------------------
// Global (N x N) cross attention, bf16 MFMA flash kernel.
// 256 blocks x 512 threads (8 waves), 64 q/block. In-block split-K:
// waves 0-3 process even 64-key tiles, waves 4-7 odd tiles; exact merge at end.
// Quad-buffered K/V (tile t -> buf t&3): prefetch never collides with reads,
// so one raw s_barrier + counted vmcnt per tile-pair (no vmcnt(0) drain).
// LDS (144KB): Q/P 0..16K | K bufs 16K..80K | V bufs 80K..144K.
// ---------------------------------------------------------------------------
#define GQOFF 0
#define GKOFF 16384
#define GVOFF 81920

struct GlobalAttnParams {
  const short *Qhb, *Qlb, *Khb, *Klb, *Vhb, *Vlb;
  float *ML, *MH;
  const float* alpha;
};

__global__ __launch_bounds__(512, 2)
void attn_gl_kernel(GlobalAttnParams p) {
  __shared__ __align__(16) char smem[147456];
  const int tid = threadIdx.x;
  const int lane = tid & 63, w = tid >> 6;     // 8 waves
  const int wid = w & 3, gsel = w >> 2;        // q-strip, tile-parity group
  const int m = lane & 15, hi = lane >> 4;

  // xcd grouping: 2 XCDs per (b,pair) -> K/V (2MB) fits the 4MB XCD L2
  const int bx = blockIdx.x;
  const int xcd = bx & 7, sub = bx >> 3;       // sub 0..31
  const int pz = xcd >> 1;
  const int b = pz >> 1, pair = pz & 1;
  const int q0 = ((xcd & 1) * 32 + sub) * 64;

  const short* Qb = (pair ? p.Qlb : p.Qhb) + (size_t)b * N_ * D_;
  const short* Kb = (pair ? p.Khb : p.Klb) + (size_t)b * N_ * D_;
  const short* Vb = (pair ? p.Vhb : p.Vlb) + (size_t)b * D_ * N_;
  float* M = (pair ? p.MH : p.ML) + (size_t)b * D_ * N_;

  float a0 = p.alpha[0], a1 = p.alpha[1], a2 = p.alpha[2], a3 = p.alpha[3];
  float am = fmaxf(fmaxf(a0,a1), fmaxf(a2,a3));
  float e0 = __expf(a0-am), e1 = __expf(a1-am), e2 = __expf(a2-am), e3 = __expf(a3-am);
  const float wsel = e3 / (e0+e1+e2+e3);

  // stage tiles 2p, 2p+1 into bufs (2p)&3, (2p+1)&3 (8 loads per wave)
  auto stagePair = [&](int pp) {
    #pragma unroll
    for (int i = 0; i < 4; ++i) {
      int c = w*4 + i;                 // 0..31
      int tl = 2*pp + (c >> 4);
      int idx = c & 15;                // 1KB chunk within tile
      int kb = tl & 3;
      gl_lds16(Kb + (size_t)tl*8192 + idx*512 + lane*8,
               smem + GKOFF + kb*16384 + idx*1024);
      gl_lds16(Vb + (size_t)(idx*8 + (lane>>3))*N_ + tl*64 + (lane&7)*8,
               smem + GVOFF + kb*16384 + idx*1024);
    }
  };

  // prologue: stage Q (2 chunks/wave), then pairs 0,1
  #pragma unroll
  for (int i = 0; i < 2; ++i) {
    int chunk = w*2 + i;
    gl_lds16(Qb + (size_t)q0*D_ + chunk*512 + lane*8, smem + GQOFF + chunk*1024);
  }
  stagePair(0);
  stagePair(1);
  asm volatile("s_waitcnt vmcnt(16)" ::: "memory");   // Q landed
  __builtin_amdgcn_s_barrier();
  __builtin_amdgcn_sched_barrier(0);

  // hoist Q fragments (A-operand rows = wave's 16 queries)
  const int qrow = wid*16 + m;
  short8 qf[4];
  #pragma unroll
  for (int cs = 0; cs < 4; ++cs)
    qf[cs] = *(const short8*)(smem + GQOFF + qrow*256 + ((cs*64 + hi*16) ^ ((qrow&7)<<4)));
  asm volatile("s_waitcnt lgkmcnt(0)" ::: "memory");
  __builtin_amdgcn_sched_barrier(0);
  __builtin_amdgcn_s_barrier();     // Q region becomes the P strips

  f32x4 oacc[8];
  #pragma unroll
  for (int i = 0; i < 8; ++i) oacc[i] = (f32x4){0.f,0.f,0.f,0.f};
  float m_run[4] = {-INFINITY,-INFINITY,-INFINITY,-INFINITY};
  float l_run[4] = {0.f,0.f,0.f,0.f};

  const int NP = N_ / 128;          // 32 tile-pairs
  char* const pstrip = smem + w*2048;
  for (int j = 0; j < NP; ++j) {
    if (j + 2 < NP) stagePair(j + 2);
    if (j + 2 < NP)      { asm volatile("s_waitcnt vmcnt(16)" ::: "memory"); }
    else if (j + 1 < NP) { asm volatile("s_waitcnt vmcnt(8)"  ::: "memory"); }
    else                 { asm volatile("s_waitcnt vmcnt(0)"  ::: "memory"); }
    __builtin_amdgcn_s_barrier();
    __builtin_amdgcn_sched_barrier(0);

    const int t = 2*j + gsel;       // my tile this iteration
    const int kb = t & 3;
    const char* Kc = smem + GKOFF + kb*16384;
    const char* Vc = smem + GVOFF + kb*16384;

    // ---- S = Q K^T ----
    f32x4 sacc[4];
    #pragma unroll
    for (int kf = 0; kf < 4; ++kf) sacc[kf] = (f32x4){0.f,0.f,0.f,0.f};
    __builtin_amdgcn_s_setprio(1);
    #pragma unroll
    for (int kf = 0; kf < 4; ++kf) {
      const int krow = kf*16 + m;
      const char* kr = Kc + krow*256;
      #pragma unroll
      for (int cs = 0; cs < 4; ++cs) {
        short8 kfr = *(const short8*)(kr + ((cs*64 + hi*16) ^ ((krow&7)<<4)));
        sacc[kf] = __builtin_amdgcn_mfma_f32_16x16x32_bf16(qf[cs], kfr, sacc[kf], 0,0,0);
      }
    }
    __builtin_amdgcn_s_setprio(0);

    // ---- online softmax (log2 domain; scl*log2e folded into Q) ----
    #pragma unroll
    for (int r = 0; r < 4; ++r) {
      float mt = fmaxf(fmaxf(sacc[0][r], sacc[1][r]), fmaxf(sacc[2][r], sacc[3][r]));
      mt = fmaxf(mt, __shfl_xor(mt, 1));
      mt = fmaxf(mt, __shfl_xor(mt, 2));
      mt = fmaxf(mt, __shfl_xor(mt, 4));
      mt = fmaxf(mt, __shfl_xor(mt, 8));
      float mn = fmaxf(m_run[r], mt);
      float corr = EXP2(m_run[r] - mn);
      m_run[r] = mn;
      const int rl = hi*4 + r;           // local P row (C/D layout, m89)
      char* prow = pstrip + rl*128;
      float psum = 0.f;
      #pragma unroll
      for (int kf = 0; kf < 4; ++kf) {
        float pv = EXP2(sacc[kf][r] - mn);
        psum += pv;
        int kcol = (kf*16 + m)*2;
        *(short*)(prow + (kcol ^ ((rl&7)<<4))) = f2bf(pv);
      }
      psum += __shfl_xor(psum, 1);
      psum += __shfl_xor(psum, 2);
      psum += __shfl_xor(psum, 4);
      psum += __shfl_xor(psum, 8);
      l_run[r] = l_run[r]*corr + psum;
      #pragma unroll
      for (int cf = 0; cf < 8; ++cf) oacc[cf][r] *= corr;
    }

    // ---- O += P V^T (P strip per-wave private; DS in-order) ----
    __builtin_amdgcn_s_setprio(1);
    #pragma unroll
    for (int ks = 0; ks < 2; ++ks) {
      short8 pa = *(const short8*)(pstrip + m*128 + ((ks*64 + hi*16) ^ ((m&7)<<4)));
      #pragma unroll
      for (int cf = 0; cf < 8; ++cf) {
        const int crow = cf*16 + m;
        short8 vf = *(const short8*)(Vc + crow*128 + ((ks*64 + hi*16) ^ ((crow&7)<<4)));
        oacc[cf] = __builtin_amdgcn_mfma_f32_16x16x32_bf16(pa, vf, oacc[cf], 0,0,0);
      }
    }
    __builtin_amdgcn_s_setprio(0);
  }
  __syncthreads();

  // ---- merge group B (odd tiles) into group A (even tiles) ----
  // B partials: O at 16K + wid*8K (32 f32/lane), m/l at 48K + wid*2K.
  float* OB = (float*)(smem + 16384 + wid*8192);
  float* MLB = (float*)(smem + 49152 + wid*2048);
  if (gsel == 1) {
    #pragma unroll
    for (int cf = 0; cf < 8; ++cf)
      #pragma unroll
      for (int r = 0; r < 4; ++r)
        OB[(cf*4 + r)*64 + lane] = oacc[cf][r];
    #pragma unroll
    for (int r = 0; r < 4; ++r) {
      MLB[r*64 + lane] = m_run[r];
      MLB[(4+r)*64 + lane] = l_run[r];
    }
  }
  __syncthreads();

  if (gsel == 0) {
    float inv[4];
    #pragma unroll
    for (int r = 0; r < 4; ++r) {
      float mB = MLB[r*64 + lane];
      float lB = MLB[(4+r)*64 + lane];
      float mn = fmaxf(m_run[r], mB);
      float cA = EXP2(m_run[r] - mn);
      float cB = EXP2(mB - mn);
      float l = l_run[r]*cA + lB*cB;
      inv[r] = wsel / l;
      #pragma unroll
      for (int cf = 0; cf < 8; ++cf)
        oacc[cf][r] = oacc[cf][r]*cA + OB[(cf*4 + r)*64 + lane]*cB;
    }
    // transpose via LDS at 56K (Os[128][66] f32)
    float* Os = (float*)(smem + 57344);
    #pragma unroll
    for (int cf = 0; cf < 8; ++cf)
      #pragma unroll
      for (int r = 0; r < 4; ++r)
        Os[(cf*16 + m)*66 + wid*16 + hi*4 + r] = oacc[cf][r] * inv[r];
  }
  __syncthreads();

  const float* Os = (const float*)(smem + 57344);
  for (int it = 0; it < 16; ++it) {
    int flat = it*512 + tid;
    int c = flat >> 6, qq = flat & 63;
    M[(size_t)c*N_ + q0 + qq] = Os[c*66 + qq];   // store (global term first)
  }
}

// ---------------------------------------------------------------------------
// f32 flash-attention kernel (axial row/col + diag paths).
// ---------------------------------------------------------------------------
struct AttnParams {
  const float *Qh, *Ql, *Kh, *Kl, *Vh, *Vl;
  float *ML, *MH;
  const float *alpha;
  int seq_mult, pos_stride, Lk, Lq, widx, store_mode, diag;
};

__global__ __launch_bounds__(256, 1)
void attn_kernel(AttnParams p) {
  __shared__ __align__(16) float Qs[128][68];
  __shared__ __align__(16) float Ks[128][68];
  __shared__ __align__(16) float Vs[128][68];
  __shared__ __align__(16) float Ps[64][68];

  const int tid = threadIdx.x;
  const int tx = tid & 15;
  const int ty = tid >> 4;
  const int b = blockIdx.z >> 1, pair = blockIdx.z & 1;

  const float* Q = pair ? p.Ql : p.Qh;
  const float* K = pair ? p.Kh : p.Kl;
  const float* V = pair ? p.Vh : p.Vl;
  float* M = pair ? p.MH : p.ML;
  const size_t boff = (size_t)b * D_ * N_;
  Q += boff; K += boff; V += boff; M += boff;

  float a0 = p.alpha[0], a1 = p.alpha[1], a2 = p.alpha[2], a3 = p.alpha[3];
  float am = fmaxf(fmaxf(a0, a1), fmaxf(a2, a3));
  float e0 = __expf(a0-am), e1 = __expf(a1-am), e2 = __expf(a2-am), e3 = __expf(a3-am);
  float wsel = (p.widx==0 ? e0 : p.widx==1 ? e1 : p.widx==2 ? e2 : e3) / (e0+e1+e2+e3);

  const int seq_off = blockIdx.y * p.seq_mult;
  const int q0 = blockIdx.x << 6;
  const float scl = 0.08838834764831845f;

  for (int r = 0; r < 32; ++r) {
    int flat = (r << 8) + tid;
    int c = flat >> 6, qq = flat & 63;
    int qi = q0 + qq; qi = qi < p.Lq ? qi : p.Lq - 1;
    Qs[c][qq] = Q[(size_t)c * N_ + seq_off + (size_t)qi * p.pos_stride];
  }

  float o[4][8];
  #pragma unroll
  for (int i = 0; i < 4; ++i)
    #pragma unroll
    for (int u = 0; u < 8; ++u) o[i][u] = 0.f;
  float m_run[4] = {-INFINITY, -INFINITY, -INFINITY, -INFINITY};
  float l_run[4] = {0.f, 0.f, 0.f, 0.f};

  const int ntiles = (p.Lk + 63) >> 6;
  for (int kt = 0; kt < ntiles; ++kt) {
    const int kbase = kt << 6;
    __syncthreads();
    for (int r = 0; r < 32; ++r) {
      int flat = (r << 8) + tid;
      int c = flat >> 6, kk = flat & 63;
      int ki = kbase + kk;
      Ks[c][kk] = (ki < p.Lk) ? K[(size_t)c*N_ + seq_off + (size_t)ki*p.pos_stride] : 0.f;
    }
    for (int r = 0; r < 32; ++r) {
      int flat = (r << 8) + tid;
      int c = flat >> 6, kk = flat & 63;
      int ki = kbase + kk;
      Vs[c][kk] = (ki < p.Lk) ? V[(size_t)c*N_ + seq_off + (size_t)ki*p.pos_stride] : 0.f;
    }
    __syncthreads();

    float s[4][4];
    #pragma unroll
    for (int i = 0; i < 4; ++i)
      #pragma unroll
      for (int j = 0; j < 4; ++j) s[i][j] = 0.f;

    #pragma unroll 4
    for (int c = 0; c < 128; ++c) {
      float4 qv = *(const float4*)&Qs[c][ty << 2];
      float4 kv = *(const float4*)&Ks[c][tx << 2];
      s[0][0] += qv.x*kv.x; s[0][1] += qv.x*kv.y; s[0][2] += qv.x*kv.z; s[0][3] += qv.x*kv.w;
      s[1][0] += qv.y*kv.x; s[1][1] += qv.y*kv.y; s[1][2] += qv.y*kv.z; s[1][3] += qv.y*kv.w;
      s[2][0] += qv.z*kv.x; s[2][1] += qv.z*kv.y; s[2][2] += qv.z*kv.z; s[2][3] += qv.z*kv.w;
      s[3][0] += qv.w*kv.x; s[3][1] += qv.w*kv.y; s[3][2] += qv.w*kv.z; s[3][3] += qv.w*kv.w;
    }

    float cw[4];
    #pragma unroll
    for (int j = 0; j < 4; ++j) {
      int kg = kbase + (tx << 2) + j;
      float v = (kg < p.Lk) ? 1.f : 0.f;
      if (p.diag) {
        int dd = kg - 63; dd = dd < 0 ? -dd : dd;
        v = (kg < p.Lk) ? (float)(64 - dd) : 0.f;
      }
      cw[j] = v;
    }

    #pragma unroll
    for (int i = 0; i < 4; ++i) {
      float mt = -INFINITY;
      #pragma unroll
      for (int j = 0; j < 4; ++j) { s[i][j] *= scl; mt = fmaxf(mt, s[i][j]); }
      #pragma unroll
      for (int off = 1; off < 16; off <<= 1) mt = fmaxf(mt, __shfl_xor(mt, off, 64));
      float mn = fmaxf(m_run[i], mt);
      float corr = __expf(m_run[i] - mn);
      m_run[i] = mn;
      float pj0 = cw[0] * __expf(s[i][0] - mn);
      float pj1 = cw[1] * __expf(s[i][1] - mn);
      float pj2 = cw[2] * __expf(s[i][2] - mn);
      float pj3 = cw[3] * __expf(s[i][3] - mn);
      float rs = pj0 + pj1 + pj2 + pj3;
      #pragma unroll
      for (int off = 1; off < 16; off <<= 1) rs += __shfl_xor(rs, off, 64);
      l_run[i] = l_run[i] * corr + rs;
      #pragma unroll
      for (int u = 0; u < 8; ++u) o[i][u] *= corr;
      *(float4*)&Ps[(ty<<2)+i][tx<<2] = make_float4(pj0, pj1, pj2, pj3);
    }
    __syncthreads();

    #pragma unroll 2
    for (int k4 = 0; k4 < 16; ++k4) {
      float4 p0 = *(const float4*)&Ps[(ty<<2)+0][k4<<2];
      float4 p1 = *(const float4*)&Ps[(ty<<2)+1][k4<<2];
      float4 p2 = *(const float4*)&Ps[(ty<<2)+2][k4<<2];
      float4 p3 = *(const float4*)&Ps[(ty<<2)+3][k4<<2];
      #pragma unroll
      for (int u = 0; u < 8; ++u) {
        float4 v4 = *(const float4*)&Vs[tx + (u<<4)][k4<<2];
        o[0][u] += p0.x*v4.x + p0.y*v4.y + p0.z*v4.z + p0.w*v4.w;
        o[1][u] += p1.x*v4.x + p1.y*v4.y + p1.z*v4.z + p1.w*v4.w;
        o[2][u] += p2.x*v4.x + p2.y*v4.y + p2.z*v4.z + p2.w*v4.w;
        o[3][u] += p3.x*v4.x + p3.y*v4.y + p3.z*v4.z + p3.w*v4.w;
      }
    }
  }

  __syncthreads();
  #pragma unroll
  for (int i = 0; i < 4; ++i) {
    float sc = wsel / l_run[i];
    #pragma unroll
    for (int u = 0; u < 8; ++u)
      Qs[tx + (u<<4)][(ty<<2)+i] = o[i][u] * sc;
  }
  __syncthreads();
  for (int r = 0; r < 32; ++r) {
    int flat = (r << 8) + tid;
    int c = flat >> 6, qq = flat & 63;
    int qi = q0 + qq;
    if (qi < p.Lq) {
      size_t addr = (size_t)c*N_ + seq_off + (size_t)qi*p.pos_stride;
      float v = Qs[c][qq];
      if (p.store_mode) M[addr] = v; else M[addr] += v;
    }
  }
}

// ---------------------------------------------------------------------------
// Tiled GEMM: Y[o][n] = sum_c Wm[o][c]*X[c][n] (+bias[o]) (+res[o][n])
// ---------------------------------------------------------------------------
struct GemmParams {
  const float *Wm, *X, *res, *bias;
  float *Y;
  int O, K;
  long long sx, sy, sres;
};

__global__ __launch_bounds__(256, 2)
void gemm_kernel(GemmParams g) {
  __shared__ __align__(16) float Wt[32][68];
  __shared__ __align__(16) float Xt[32][68];
  const int tid = threadIdx.x;
  const int tx = tid & 15, ty = tid >> 4;
  const int n0 = blockIdx.x << 6;
  const int ot0 = blockIdx.y << 6;
  const int b = blockIdx.z;

  const float* X = g.X + (long long)b * g.sx;
  float* Y = g.Y + (long long)b * g.sy;
  const float* res = g.res ? (g.res + (long long)b * g.sres) : nullptr;

  float acc[4][4];
  #pragma unroll
  for (int i = 0; i < 4; ++i)
    #pragma unroll
    for (int j = 0; j < 4; ++j) acc[i][j] = 0.f;

  for (int c0 = 0; c0 < g.K; c0 += 32) {
    __syncthreads();
    #pragma unroll
    for (int r = 0; r < 8; ++r) {
      int flat = (r << 8) + tid;
      int oo = flat >> 5, c = flat & 31;
      Wt[c][oo] = g.Wm[(size_t)(ot0 + oo) * g.K + c0 + c];
    }
    #pragma unroll
    for (int r = 0; r < 8; ++r) {
      int flat = (r << 8) + tid;
      int c = flat >> 6, nn = flat & 63;
      Xt[c][nn] = X[(size_t)(c0 + c) * N_ + n0 + nn];
    }
    __syncthreads();
    #pragma unroll 8
    for (int c = 0; c < 32; ++c) {
      float4 wv = *(const float4*)&Wt[c][ty << 2];
      float4 xv = *(const float4*)&Xt[c][tx << 2];
      acc[0][0] += wv.x*xv.x; acc[0][1] += wv.x*xv.y; acc[0][2] += wv.x*xv.z; acc[0][3] += wv.x*xv.w;
      acc[1][0] += wv.y*xv.x; acc[1][1] += wv.y*xv.y; acc[1][2] += wv.y*xv.z; acc[1][3] += wv.y*xv.w;
      acc[2][0] += wv.z*xv.x; acc[2][1] += wv.z*xv.y; acc[2][2] += wv.z*xv.z; acc[2][3] += wv.z*xv.w;
      acc[3][0] += wv.w*xv.x; acc[3][1] += wv.w*xv.y; acc[3][2] += wv.w*xv.z; acc[3][3] += wv.w*xv.w;
    }
  }

  #pragma unroll
  for (int i = 0; i < 4; ++i) {
    int oo = ot0 + (ty << 2) + i;
    float bv = g.bias ? g.bias[oo] : 0.f;
    float4 outv = make_float4(acc[i][0]+bv, acc[i][1]+bv, acc[i][2]+bv, acc[i][3]+bv);
    if (res) {
      float4 r4 = *(const float4*)&res[(size_t)oo*N_ + n0 + (tx<<2)];
      outv.x += r4.x; outv.y += r4.y; outv.z += r4.z; outv.w += r4.w;
    }
    *(float4*)&Y[(size_t)oo*N_ + n0 + (tx<<2)] = outv;
  }
}

// ---------------------------------------------------------------------------
extern "C" void kernel_launch(void* const* d_in, const int* in_sizes, int n_in,
                              void* d_out, int out_size, void* d_ws, size_t ws_size,
                              hipStream_t stream) {
  (void)in_sizes; (void)n_in; (void)out_size; (void)ws_size;
  const float* ll  = (const float*)d_in[0];
  const float* hf  = (const float*)d_in[1];
  const float* Wqh = (const float*)d_in[2];
  const float* Wkh = (const float*)d_in[3];
  const float* Wvh = (const float*)d_in[4];
  const float* Wql = (const float*)d_in[5];
  const float* Wkl = (const float*)d_in[6];
  const float* Wvl = (const float*)d_in[7];
  const float* Wph = (const float*)d_in[8];
  const float* bph = (const float*)d_in[9];
  const float* Wpl = (const float*)d_in[10];
  const float* bpl = (const float*)d_in[11];
  const float* Wah = (const float*)d_in[12];
  const float* bah = (const float*)d_in[13];
  const float* Wal = (const float*)d_in[14];
  const float* bal = (const float*)d_in[15];
  const float* alpha = (const float*)d_in[16];

  float* ws = (float*)d_ws;
  const size_t BDN = (size_t)B_ * D_ * N_;   // 1048576
  float* Qh = ws;
  float* Kh = Qh + BDN;
  float* Vh = Kh + BDN;
  float* Ql = Vh + BDN;
  float* Kl = Ql + BDN;
  float* Vl = Kl + BDN;
  float* ML = Vl + BDN;
  float* MH = ML + BDN;
  float* Ul = MH + BDN;
  float* Uh = Ul + (size_t)B_ * CL_ * N_;
  short* Qhb = (short*)(Uh + (size_t)B_ * CH_ * N_);
  short* Qlb = Qhb + BDN;
  short* Khb = Qlb + BDN;
  short* Klb = Khb + BDN;
  short* Vhb = Klb + BDN;
  short* Vlb = Vhb + BDN;

  dim3 blk(256, 1, 1);
  const long long sLL = (long long)CL_ * N_;
  const long long sHF = (long long)CH_ * N_;
  const long long sDN = (long long)D_  * N_;
  const float qscale = (float)(0.08838834764831845 * 1.4426950408889634);

  // fused QKV projections + bf16 swizzled copies (one kernel per stream)
  {
    QkvParams qh{hf, Wqh, Wkh, Wvh, Qh, Kh, Vh, Qhb, Khb, Vhb, CH_, qscale};
    qkv_kernel<<<dim3(N_/64, 6, B_), blk, 0, stream>>>(qh);
    QkvParams ql{ll, Wql, Wkl, Wvl, Ql, Kl, Vl, Qlb, Klb, Vlb, CL_, qscale};
    qkv_kernel<<<dim3(N_/64, 6, B_), blk, 0, stream>>>(ql);
  }

  // global attention (MFMA split-K, stores M with w[3])
  GlobalAttnParams gp{Qhb, Qlb, Khb, Klb, Vhb, Vlb, ML, MH, alpha};
  attn_gl_kernel<<<dim3(256, 1, 1), dim3(512,1,1), 0, stream>>>(gp);

  // axial + diag (f32, accumulate)
  auto attn = [&](int gx, int gy, int seq_mult, int pos_stride, int Lk, int Lq,
                  int widx, int store_mode, int diag) {
    AttnParams p{Qh, Ql, Kh, Kl, Vh, Vl, ML, MH, alpha,
                 seq_mult, pos_stride, Lk, Lq, widx, store_mode, diag};
    attn_kernel<<<dim3(gx, gy, 2*B_), blk, 0, stream>>>(p);
  };
  attn(1, 64, 64, 1, 64, 64, 0, 0, 0);   // rows   (w[0])
  attn(1, 64, 1, 64, 64, 64, 1, 0, 0);   // cols   (w[1])
  attn(2, 1, 0, 1, 127, 127, 2, 0, 1);   // diag   (w[2], count weights)

  auto gemm = [&](const float* W, const float* X, const float* res, const float* bias,
                  float* Y, int O, int K, long long sx, long long sy, long long sres) {
    GemmParams g{W, X, res, bias, Y, O, K, sx, sy, sres};
    gemm_kernel<<<dim3(N_/64, O/64, B_), blk, 0, stream>>>(g);
  };

  // U = x + Wp @ M + bp   (wdir sums to 1 -> single bias application)
  gemm(Wpl, ML, ll, bpl, Ul, CL_, D_, sDN, sLL, sLL);
  gemm(Wph, MH, hf, bph, Uh, CH_, D_, sDN, sHF, sHF);

  // final: out = Wa @ U + ba
  float* out = (float*)d_out;
  gemm(Wal, Ul, nullptr, bal, out,                          CL_, CL_, sLL, sLL, 0);
  gemm(Wah, Uh, nullptr, bah, out + (size_t)B_ * CL_ * N_,  CH_, CH_, sHF, sHF, 0);
}

// Round 6
// 192.454 us; speedup vs baseline: 8.7489x; 1.8878x over previous
//
#include <hip/hip_runtime.h>
#include <math.h>

#define N_  4096
#define D_  128
#define B_  2
#define CL_ 64
#define CH_ 192

typedef __attribute__((ext_vector_type(8))) short short8;
typedef __attribute__((ext_vector_type(4))) float f32x4;

#if __has_builtin(__builtin_amdgcn_exp2f)
#define EXP2(x) __builtin_amdgcn_exp2f(x)
#else
#define EXP2(x) exp2f(x)
#endif

__device__ __forceinline__ short f2bf(float x) {
  union { float f; unsigned u; } v; v.f = x;
  unsigned r = v.u + 0x7FFFu + ((v.u >> 16) & 1u);
  return (short)(r >> 16);
}

typedef __attribute__((address_space(1))) const void gv_t;
typedef __attribute__((address_space(3))) void sv_t;
__device__ __forceinline__ void gl_lds16(const void* g, void* l) {
  __builtin_amdgcn_global_load_lds((gv_t*)g, (sv_t*)l, 16, 0, 0);
}

// ---------------------------------------------------------------------------
// XT: f32 [C][4096] -> bf16 [n][C], granule (8 elems) pre-swizzled ^(n&7)
// within each 8-granule (64-elem) window.
// ---------------------------------------------------------------------------
__global__ __launch_bounds__(256)
void xt_kernel(const float* __restrict__ src, short* __restrict__ dst, int C) {
  __shared__ float Ls[CH_][65];
  const int tid = threadIdx.x;
  const int n0 = blockIdx.x * 64;
  const int b = blockIdx.y;
  src += (size_t)b * C * N_;
  dst += (size_t)b * N_ * C;
  for (int flat = tid; flat < C * 64; flat += 256) {
    int c = flat >> 6, nn = flat & 63;
    Ls[c][nn] = src[(size_t)c * N_ + n0 + nn];
  }
  __syncthreads();
  const int ng = C >> 3;
  for (int u = tid; u < 64 * ng; u += 256) {
    int nn = u / ng, g = u - nn * ng;
    short8 v;
    #pragma unroll
    for (int j = 0; j < 8; ++j) v[j] = f2bf(Ls[g*8 + j][nn]);
    int pos = (g & ~7) | ((g ^ (nn & 7)) & 7);
    *(short8*)(dst + (size_t)(n0 + nn) * C + pos * 8) = v;
  }
}

// ---------------------------------------------------------------------------
// Vt: Vb bf16 [d][n] (granule ^(d&7) in 64-blocks) -> image-transposed
// Vt [d][n'] (n' = w*64+h), same swizzle. In-register 8x8 transpose.
// ---------------------------------------------------------------------------
__global__ __launch_bounds__(256)
void vt_kernel(const short* __restrict__ Vhb, const short* __restrict__ Vlb,
               short* __restrict__ Vht, short* __restrict__ Vlt) {
  __shared__ short rowbuf[4 * 4096];
  const int tid = threadIdx.x;
  const int lane = tid & 63, w = tid >> 6;
  const short* src = blockIdx.y ? Vlb : Vhb;
  short* dst = blockIdx.y ? Vlt : Vht;
  const int r0 = blockIdx.x * 4;                  // 4 rows of [2b x 128d]
  #pragma unroll
  for (int i = 0; i < 8; ++i) {
    int idx = i * 256 + w * 64 + lane;            // 2048 granules of 16B
    int row = idx >> 9, g = idx & 511;
    gl_lds16(src + (size_t)(r0 + row) * N_ + g * 8,
             (char*)rowbuf + i * 4096 + w * 1024 + lane * 16);
  }
  __syncthreads();
  const int rw = r0 + w, d7 = rw & 7;
  const short* rb = rowbuf + w * 4096;
  const int w0 = (lane & 7) * 8, h0 = (lane >> 3) * 8;
  short8 rr[8];
  #pragma unroll
  for (int j = 0; j < 8; ++j)
    rr[j] = *(const short8*)(rb + (h0 + j) * 64 + (((w0 >> 3) ^ d7) * 8));
  #pragma unroll
  for (int i = 0; i < 8; ++i) {
    short8 o;
    #pragma unroll
    for (int j = 0; j < 8; ++j) o[j] = rr[j][i];
    *(short8*)(dst + (size_t)rw * N_ + (w0 + i) * 64 + (((h0 >> 3) ^ d7) * 8)) = o;
  }
}

// ---------------------------------------------------------------------------
// Unified bf16 MFMA GEMM: Y[o][n] = W[o][c] * X[c][n]
// A: W f32 -> bf16 LDS (swizzled) in-kernel. B: bf16 [n][K] pre-swizzled src,
// staged linearly via global_load_lds. Tile 64o x 64n, 4 waves, K-step 64.
// epmode 0: qkv (blockIdx.y = sel*2+dhalf; emits Qb/Kb+Qt/Kt or Vb)
// epmode 1: proj  (res + bias; emits Ut bf16 [n][O] swizzled)
// epmode 2: final (bias; emits f32 [o][n])
// ---------------------------------------------------------------------------
struct GemmP {
  const float *W0, *W1, *W2;
  const short *Bsrc;
  const float *res, *bias;
  float *outF;
  short *Qb, *Kb, *Vb, *Qt, *Kt;
  short *Ut;
  int K, O, epmode;
  float qscale;
};

__global__ __launch_bounds__(256, 4)
void gemm_bf16(GemmP g) {
  __shared__ __align__(16) char AB[16384];        // A 0..8K, B 8K..16K
  __shared__ float Epi[64][67];
  const int tid = threadIdx.x;
  const int lane = tid & 63, w = tid >> 6, m = lane & 15, hi = lane >> 4;
  const int n0 = blockIdx.x * 64;
  const int b = blockIdx.z;
  int sel = 0, dhalf = 0, ot0;
  const float* Wm;
  if (g.epmode == 0) {
    sel = blockIdx.y >> 1; dhalf = blockIdx.y & 1; ot0 = dhalf * 64;
    Wm = sel == 0 ? g.W0 : sel == 1 ? g.W1 : g.W2;
  } else {
    ot0 = blockIdx.y * 64; Wm = g.W0;
  }
  const short* Bs = g.Bsrc + (size_t)b * N_ * g.K;

  f32x4 acc[4];
  #pragma unroll
  for (int i = 0; i < 4; ++i) acc[i] = (f32x4){0.f, 0.f, 0.f, 0.f};

  for (int c0 = 0; c0 < g.K; c0 += 64) {
    __syncthreads();
    {   // stage A (f32 -> bf16, swizzled ^(o&7))
      int o = tid >> 2, cq = tid & 3;
      const float* wp = Wm + (size_t)(ot0 + o) * g.K + c0 + cq * 16;
      float4 fa = *(const float4*)(wp + 0);
      float4 fb = *(const float4*)(wp + 4);
      float4 fc = *(const float4*)(wp + 8);
      float4 fd = *(const float4*)(wp + 12);
      short8 v0 = { f2bf(fa.x), f2bf(fa.y), f2bf(fa.z), f2bf(fa.w),
                    f2bf(fb.x), f2bf(fb.y), f2bf(fb.z), f2bf(fb.w) };
      short8 v1 = { f2bf(fc.x), f2bf(fc.y), f2bf(fc.z), f2bf(fc.w),
                    f2bf(fd.x), f2bf(fd.y), f2bf(fd.z), f2bf(fd.w) };
      int g0 = cq * 2;
      *(short8*)(AB + o * 128 + (((g0) ^ (o & 7)) * 16)) = v0;
      *(short8*)(AB + o * 128 + (((g0 + 1) ^ (o & 7)) * 16)) = v1;
    }
    // stage B: linear copy of pre-swizzled bytes (lds dest = base + lane*16)
    #pragma unroll
    for (int e = 0; e < 2; ++e) {
      int cid = e * 256 + w * 64 + lane;
      int nn = cid >> 3, gs = cid & 7;
      gl_lds16(Bs + (size_t)(n0 + nn) * g.K + c0 + gs * 8,
               AB + 8192 + e * 4096 + w * 1024 + lane * 16);
    }
    __syncthreads();
    const int orow = w * 16 + m;
    short8 a0 = *(const short8*)(AB + orow * 128 + (((hi) ^ (orow & 7)) * 16));
    short8 a1 = *(const short8*)(AB + orow * 128 + (((4 + hi) ^ (orow & 7)) * 16));
    #pragma unroll
    for (int nf = 0; nf < 4; ++nf) {
      int nrow = nf * 16 + m;
      short8 b0 = *(const short8*)(AB + 8192 + nrow * 128 + (((hi) ^ (nrow & 7)) * 16));
      short8 b1 = *(const short8*)(AB + 8192 + nrow * 128 + (((4 + hi) ^ (nrow & 7)) * 16));
      acc[nf] = __builtin_amdgcn_mfma_f32_16x16x32_bf16(a0, b0, acc[nf], 0, 0, 0);
      acc[nf] = __builtin_amdgcn_mfma_f32_16x16x32_bf16(a1, b1, acc[nf], 0, 0, 0);
    }
  }

  // stage C/D tile to LDS f32 [o][n]
  #pragma unroll
  for (int nf = 0; nf < 4; ++nf)
    #pragma unroll
    for (int r = 0; r < 4; ++r)
      Epi[w * 16 + hi * 4 + r][nf * 16 + m] = acc[nf][r];
  __syncthreads();

  if (g.epmode == 0) {
    if (sel < 2) {
      float sc = (sel == 0) ? g.qscale : 1.f;
      short* QK = (sel == 0 ? g.Qb : g.Kb) + (size_t)b * N_ * D_;
      short* QKt = (sel == 0 ? g.Qt : g.Kt) + (size_t)b * N_ * D_;
      const int bx = blockIdx.x;
      #pragma unroll
      for (int e = 0; e < 2; ++e) {
        int u = tid + 256 * e;
        int nn = u >> 3, gl = u & 7;
        short8 v;
        #pragma unroll
        for (int j = 0; j < 8; ++j) v[j] = f2bf(Epi[gl*8 + j][nn] * sc);
        int posb = (dhalf * 8) | ((gl ^ (nn & 7)) & 7);
        *(short8*)(QK + (size_t)(n0 + nn) * D_ + posb * 8) = v;
        int post = (dhalf * 8) | ((gl ^ (bx & 7)) & 7);
        *(short8*)(QKt + (size_t)(nn * 64 + bx) * D_ + post * 8) = v;
      }
    } else {
      short* Vb = g.Vb + (size_t)b * D_ * N_;
      #pragma unroll
      for (int e = 0; e < 2; ++e) {
        int u = tid + 256 * e;
        int o = u >> 3, gl = u & 7;
        int d = ot0 + o;
        short8 v;
        #pragma unroll
        for (int j = 0; j < 8; ++j) v[j] = f2bf(Epi[o][gl*8 + j]);
        *(short8*)(Vb + (size_t)d * N_ + n0 + ((gl ^ (d & 7)) * 8)) = v;
      }
    }
  } else if (g.epmode == 1) {
    const float* res = g.res + (size_t)b * g.O * N_;
    short* Ut = g.Ut + (size_t)b * N_ * g.O;
    #pragma unroll
    for (int e = 0; e < 2; ++e) {
      int nn = tid & 63;
      int gl = (tid >> 6) + e * 4;
      int ob = ot0 + gl * 8;
      short8 v;
      #pragma unroll
      for (int j = 0; j < 8; ++j)
        v[j] = f2bf(Epi[gl*8 + j][nn] + res[(size_t)(ob + j) * N_ + n0 + nn] + g.bias[ob + j]);
      int gout = (ot0 >> 3) + gl;
      int pos = (gout & ~7) | ((gout ^ (nn & 7)) & 7);
      *(short8*)(Ut + (size_t)(n0 + nn) * g.O + pos * 8) = v;
    }
  } else {
    int o = tid >> 2, nq = tid & 3;
    float bv = g.bias[ot0 + o];
    float* dst = g.outF + (size_t)b * g.O * N_ + (size_t)(ot0 + o) * N_ + n0 + nq * 16;
    #pragma unroll
    for (int q4 = 0; q4 < 4; ++q4) {
      float4 vv = { Epi[o][nq*16 + q4*4 + 0] + bv, Epi[o][nq*16 + q4*4 + 1] + bv,
                    Epi[o][nq*16 + q4*4 + 2] + bv, Epi[o][nq*16 + q4*4 + 3] + bv };
      *(float4*)(dst + q4 * 4) = vv;
    }
  }
}

// ---------------------------------------------------------------------------
// Small MFMA flash attention (rows / cols / diag). 4 waves x 16q = 64q/block.
// qbase = bx*64 + y*64 (array row base for Q), kcol0 = y*64 (K/V base).
// outmode: 0 store M[c][qbase+qq], 1 add M[c][qbase+qq], 2 add M[c][qq*64+y].
// cwflag: diag count weights cnt[k]=64-|k-63|, mask k>=Lk.
// ---------------------------------------------------------------------------
struct SmParams {
  const short *Qh, *Ql, *Kh, *Kl, *Vh, *Vl;
  float *ML, *MH;
  const float* alpha;
  int Lq, Lk, widx, outmode, cwflag;
};

__global__ __launch_bounds__(256, 2)
void attn_sm(SmParams p) {
  __shared__ __align__(16) char smem[49152];   // Q/P 0..16K | K 16K | V 32K
  const int tid = threadIdx.x;
  const int lane = tid & 63, w = tid >> 6, m = lane & 15, hi = lane >> 4;
  const int bz = blockIdx.z, b = bz >> 1, pair = bz & 1;
  const int y = blockIdx.y, bx = blockIdx.x;
  const int qbase = bx * 64 + y * 64;
  const int kcol0 = y * 64;

  const short* Qs = (pair ? p.Ql : p.Qh) + (size_t)b * N_ * D_;
  const short* Ks = (pair ? p.Kh : p.Kl) + (size_t)b * N_ * D_;
  const short* Vs = (pair ? p.Vh : p.Vl) + (size_t)b * D_ * N_;
  float* M = (pair ? p.MH : p.ML) + (size_t)b * D_ * N_;

  float a0 = p.alpha[0], a1 = p.alpha[1], a2 = p.alpha[2], a3 = p.alpha[3];
  float am = fmaxf(fmaxf(a0, a1), fmaxf(a2, a3));
  float e0 = __expf(a0-am), e1 = __expf(a1-am), e2 = __expf(a2-am), e3 = __expf(a3-am);
  float wsel = (p.widx == 0 ? e0 : p.widx == 1 ? e1 : e2) / (e0 + e1 + e2 + e3);

  int lqloc = p.Lq - bx * 64; if (lqloc > 64) lqloc = 64;

  auto stageK = [&](int kt) {
    #pragma unroll
    for (int i = 0; i < 4; ++i) {
      int chunk = w * 4 + i;
      gl_lds16(Ks + (size_t)(kcol0 + kt*64) * D_ + chunk * 512 + lane * 8,
               smem + 16384 + chunk * 1024);
    }
  };
  auto stageV = [&](int kt) {
    #pragma unroll
    for (int i = 0; i < 4; ++i) {
      int chunk = w * 4 + i;
      gl_lds16(Vs + (size_t)(chunk*8 + (lane>>3)) * N_ + kcol0 + kt*64 + (lane&7)*8,
               smem + 32768 + chunk * 1024);
    }
  };
  #pragma unroll
  for (int i = 0; i < 4; ++i) {
    int chunk = w * 4 + i;
    gl_lds16(Qs + (size_t)qbase * D_ + chunk * 512 + lane * 8, smem + chunk * 1024);
  }
  stageK(0); stageV(0);
  __syncthreads();

  const int qrow = w * 16 + m;
  short8 qf[4];
  #pragma unroll
  for (int cs = 0; cs < 4; ++cs)
    qf[cs] = *(const short8*)(smem + qrow * 256 + ((cs*64 + hi*16) ^ ((qrow & 7) << 4)));
  __syncthreads();   // Q region becomes P strips

  f32x4 oacc[8];
  #pragma unroll
  for (int i = 0; i < 8; ++i) oacc[i] = (f32x4){0.f, 0.f, 0.f, 0.f};
  float m_run[4] = {-INFINITY, -INFINITY, -INFINITY, -INFINITY};
  float l_run[4] = {0.f, 0.f, 0.f, 0.f};
  char* const pstrip = smem + w * 2048;
  const int NT = (p.Lk + 63) >> 6;

  for (int kt = 0; kt < NT; ++kt) {
    const char* Kc = smem + 16384;
    const char* Vc = smem + 32768;
    f32x4 sacc[4];
    #pragma unroll
    for (int kf = 0; kf < 4; ++kf) sacc[kf] = (f32x4){0.f, 0.f, 0.f, 0.f};
    #pragma unroll
    for (int kf = 0; kf < 4; ++kf) {
      const int krow = kf * 16 + m;
      const char* kr = Kc + krow * 256;
      #pragma unroll
      for (int cs = 0; cs < 4; ++cs) {
        short8 kfr = *(const short8*)(kr + ((cs*64 + hi*16) ^ ((krow & 7) << 4)));
        sacc[kf] = __builtin_amdgcn_mfma_f32_16x16x32_bf16(qf[cs], kfr, sacc[kf], 0, 0, 0);
      }
    }
    float cw[4];
    #pragma unroll
    for (int kf = 0; kf < 4; ++kf) {
      if (p.cwflag) {
        int kg = kt * 64 + kf * 16 + m;
        int dd = kg - 63; dd = dd < 0 ? -dd : dd;
        cw[kf] = (kg < p.Lk) ? (float)(64 - dd) : 0.f;
      } else cw[kf] = 1.f;
    }
    #pragma unroll
    for (int r = 0; r < 4; ++r) {
      float mt = fmaxf(fmaxf(sacc[0][r], sacc[1][r]), fmaxf(sacc[2][r], sacc[3][r]));
      mt = fmaxf(mt, __shfl_xor(mt, 1));
      mt = fmaxf(mt, __shfl_xor(mt, 2));
      mt = fmaxf(mt, __shfl_xor(mt, 4));
      mt = fmaxf(mt, __shfl_xor(mt, 8));
      float mn = fmaxf(m_run[r], mt);
      float corr = EXP2(m_run[r] - mn);
      m_run[r] = mn;
      const int rl = hi * 4 + r;
      char* prow = pstrip + rl * 128;
      float psum = 0.f;
      #pragma unroll
      for (int kf = 0; kf < 4; ++kf) {
        float pv = cw[kf] * EXP2(sacc[kf][r] - mn);
        psum += pv;
        int kcol = (kf * 16 + m) * 2;
        *(short*)(prow + (kcol ^ ((rl & 7) << 4))) = f2bf(pv);
      }
      psum += __shfl_xor(psum, 1);
      psum += __shfl_xor(psum, 2);
      psum += __shfl_xor(psum, 4);
      psum += __shfl_xor(psum, 8);
      l_run[r] = l_run[r] * corr + psum;
      #pragma unroll
      for (int cf = 0; cf < 8; ++cf) oacc[cf][r] *= corr;
    }
    #pragma unroll
    for (int ks = 0; ks < 2; ++ks) {
      short8 pa = *(const short8*)(pstrip + m * 128 + ((ks*64 + hi*16) ^ ((m & 7) << 4)));
      #pragma unroll
      for (int cf = 0; cf < 8; ++cf) {
        const int crow = cf * 16 + m;
        short8 vf = *(const short8*)(Vc + crow * 128 + ((ks*64 + hi*16) ^ ((crow & 7) << 4)));
        oacc[cf] = __builtin_amdgcn_mfma_f32_16x16x32_bf16(pa, vf, oacc[cf], 0, 0, 0);
      }
    }
    __syncthreads();
    if (kt + 1 < NT) { stageK(kt + 1); stageV(kt + 1); __syncthreads(); }
  }

  float inv[4];
  #pragma unroll
  for (int r = 0; r < 4; ++r) inv[r] = wsel / l_run[r];
  float* Os = (float*)smem;   // [128][66] overlays Q/K regions (post-sync)
  #pragma unroll
  for (int cf = 0; cf < 8; ++cf)
    #pragma unroll
    for (int r = 0; r < 4; ++r)
      Os[(cf*16 + m) * 66 + w * 16 + hi * 4 + r] = oacc[cf][r] * inv[r];
  __syncthreads();
  for (int it = 0; it < 32; ++it) {
    int flat = it * 256 + tid;
    int c = flat >> 6, qq = flat & 63;
    if (qq < lqloc) {
      float v = Os[c * 66 + qq];
      if (p.outmode == 0)      M[(size_t)c * N_ + qbase + qq] = v;
      else if (p.outmode == 1) M[(size_t)c * N_ + qbase + qq] += v;
      else                     M[(size_t)c * N_ + qq * 64 + y] += v;
    }
  }
}

// ---------------------------------------------------------------------------
// Global (N x N) attention: 256 blocks x 512 thr (8 waves), split-K parity,
// quad-buffered K/V, counted vmcnt. Runs LAST: adds prior M (rows+cols+diag)
// and emits M^T bf16 (swizzled) for the Wp MFMA GEMM.
// ---------------------------------------------------------------------------
#define GQOFF 0
#define GKOFF 16384
#define GVOFF 81920

struct GlobalAttnParams {
  const short *Qhb, *Qlb, *Khb, *Klb, *Vhb, *Vlb;
  float *ML, *MH;
  short *Mtbl, *Mtbh;
  const float* alpha;
};

__global__ __launch_bounds__(512, 2)
void attn_gl_kernel(GlobalAttnParams p) {
  __shared__ __align__(16) char smem[147456];
  const int tid = threadIdx.x;
  const int lane = tid & 63, w = tid >> 6;
  const int wid = w & 3, gsel = w >> 2;
  const int m = lane & 15, hi = lane >> 4;

  const int bx = blockIdx.x;
  const int xcd = bx & 7, sub = bx >> 3;
  const int pz = xcd >> 1;
  const int b = pz >> 1, pair = pz & 1;
  const int q0 = ((xcd & 1) * 32 + sub) * 64;

  const short* Qb = (pair ? p.Qlb : p.Qhb) + (size_t)b * N_ * D_;
  const short* Kb = (pair ? p.Khb : p.Klb) + (size_t)b * N_ * D_;
  const short* Vb = (pair ? p.Vhb : p.Vlb) + (size_t)b * D_ * N_;
  float* M = (pair ? p.MH : p.ML) + (size_t)b * D_ * N_;
  short* Mtb = (pair ? p.Mtbh : p.Mtbl) + (size_t)b * N_ * D_;

  float a0 = p.alpha[0], a1 = p.alpha[1], a2 = p.alpha[2], a3 = p.alpha[3];
  float am = fmaxf(fmaxf(a0,a1), fmaxf(a2,a3));
  float e0 = __expf(a0-am), e1 = __expf(a1-am), e2 = __expf(a2-am), e3 = __expf(a3-am);
  const float wsel = e3 / (e0+e1+e2+e3);

  auto stagePair = [&](int pp) {
    #pragma unroll
    for (int i = 0; i < 4; ++i) {
      int c = w*4 + i;
      int tl = 2*pp + (c >> 4);
      int idx = c & 15;
      int kb = tl & 3;
      gl_lds16(Kb + (size_t)tl*8192 + idx*512 + lane*8,
               smem + GKOFF + kb*16384 + idx*1024);
      gl_lds16(Vb + (size_t)(idx*8 + (lane>>3))*N_ + tl*64 + (lane&7)*8,
               smem + GVOFF + kb*16384 + idx*1024);
    }
  };

  #pragma unroll
  for (int i = 0; i < 2; ++i) {
    int chunk = w*2 + i;
    gl_lds16(Qb + (size_t)q0*D_ + chunk*512 + lane*8, smem + GQOFF + chunk*1024);
  }
  stagePair(0);
  stagePair(1);
  asm volatile("s_waitcnt vmcnt(16)" ::: "memory");
  __builtin_amdgcn_s_barrier();
  __builtin_amdgcn_sched_barrier(0);

  const int qrow = wid*16 + m;
  short8 qf[4];
  #pragma unroll
  for (int cs = 0; cs < 4; ++cs)
    qf[cs] = *(const short8*)(smem + GQOFF + qrow*256 + ((cs*64 + hi*16) ^ ((qrow&7)<<4)));
  asm volatile("s_waitcnt lgkmcnt(0)" ::: "memory");
  __builtin_amdgcn_sched_barrier(0);
  __builtin_amdgcn_s_barrier();

  f32x4 oacc[8];
  #pragma unroll
  for (int i = 0; i < 8; ++i) oacc[i] = (f32x4){0.f,0.f,0.f,0.f};
  float m_run[4] = {-INFINITY,-INFINITY,-INFINITY,-INFINITY};
  float l_run[4] = {0.f,0.f,0.f,0.f};

  const int NP = N_ / 128;
  char* const pstrip = smem + w*2048;
  for (int j = 0; j < NP; ++j) {
    if (j + 2 < NP) stagePair(j + 2);
    if (j + 2 < NP)      { asm volatile("s_waitcnt vmcnt(16)" ::: "memory"); }
    else if (j + 1 < NP) { asm volatile("s_waitcnt vmcnt(8)"  ::: "memory"); }
    else                 { asm volatile("s_waitcnt vmcnt(0)"  ::: "memory"); }
    __builtin_amdgcn_s_barrier();
    __builtin_amdgcn_sched_barrier(0);

    const int t = 2*j + gsel;
    const int kb = t & 3;
    const char* Kc = smem + GKOFF + kb*16384;
    const char* Vc = smem + GVOFF + kb*16384;

    f32x4 sacc[4];
    #pragma unroll
    for (int kf = 0; kf < 4; ++kf) sacc[kf] = (f32x4){0.f,0.f,0.f,0.f};
    __builtin_amdgcn_s_setprio(1);
    #pragma unroll
    for (int kf = 0; kf < 4; ++kf) {
      const int krow = kf*16 + m;
      const char* kr = Kc + krow*256;
      #pragma unroll
      for (int cs = 0; cs < 4; ++cs) {
        short8 kfr = *(const short8*)(kr + ((cs*64 + hi*16) ^ ((krow&7)<<4)));
        sacc[kf] = __builtin_amdgcn_mfma_f32_16x16x32_bf16(qf[cs], kfr, sacc[kf], 0,0,0);
      }
    }
    __builtin_amdgcn_s_setprio(0);

    #pragma unroll
    for (int r = 0; r < 4; ++r) {
      float mt = fmaxf(fmaxf(sacc[0][r], sacc[1][r]), fmaxf(sacc[2][r], sacc[3][r]));
      mt = fmaxf(mt, __shfl_xor(mt, 1));
      mt = fmaxf(mt, __shfl_xor(mt, 2));
      mt = fmaxf(mt, __shfl_xor(mt, 4));
      mt = fmaxf(mt, __shfl_xor(mt, 8));
      float mn = fmaxf(m_run[r], mt);
      float corr = EXP2(m_run[r] - mn);
      m_run[r] = mn;
      const int rl = hi*4 + r;
      char* prow = pstrip + rl*128;
      float psum = 0.f;
      #pragma unroll
      for (int kf = 0; kf < 4; ++kf) {
        float pv = EXP2(sacc[kf][r] - mn);
        psum += pv;
        int kcol = (kf*16 + m)*2;
        *(short*)(prow + (kcol ^ ((rl&7)<<4))) = f2bf(pv);
      }
      psum += __shfl_xor(psum, 1);
      psum += __shfl_xor(psum, 2);
      psum += __shfl_xor(psum, 4);
      psum += __shfl_xor(psum, 8);
      l_run[r] = l_run[r]*corr + psum;
      #pragma unroll
      for (int cf = 0; cf < 8; ++cf) oacc[cf][r] *= corr;
    }

    __builtin_amdgcn_s_setprio(1);
    #pragma unroll
    for (int ks = 0; ks < 2; ++ks) {
      short8 pa = *(const short8*)(pstrip + m*128 + ((ks*64 + hi*16) ^ ((m&7)<<4)));
      #pragma unroll
      for (int cf = 0; cf < 8; ++cf) {
        const int crow = cf*16 + m;
        short8 vf = *(const short8*)(Vc + crow*128 + ((ks*64 + hi*16) ^ ((crow&7)<<4)));
        oacc[cf] = __builtin_amdgcn_mfma_f32_16x16x32_bf16(pa, vf, oacc[cf], 0,0,0);
      }
    }
    __builtin_amdgcn_s_setprio(0);
  }
  __syncthreads();

  float* OB = (float*)(smem + 16384 + wid*8192);
  float* MLB = (float*)(smem + 49152 + wid*2048);
  if (gsel == 1) {
    #pragma unroll
    for (int cf = 0; cf < 8; ++cf)
      #pragma unroll
      for (int r = 0; r < 4; ++r)
        OB[(cf*4 + r)*64 + lane] = oacc[cf][r];
    #pragma unroll
    for (int r = 0; r < 4; ++r) {
      MLB[r*64 + lane] = m_run[r];
      MLB[(4+r)*64 + lane] = l_run[r];
    }
  }
  __syncthreads();

  float* Os = (float*)(smem + 57344);   // [128][66]
  if (gsel == 0) {
    float inv[4];
    #pragma unroll
    for (int r = 0; r < 4; ++r) {
      float mB = MLB[r*64 + lane];
      float lB = MLB[(4+r)*64 + lane];
      float mn = fmaxf(m_run[r], mB);
      float cA = EXP2(m_run[r] - mn);
      float cB = EXP2(mB - mn);
      float l = l_run[r]*cA + lB*cB;
      inv[r] = wsel / l;
      #pragma unroll
      for (int cf = 0; cf < 8; ++cf)
        oacc[cf][r] = oacc[cf][r]*cA + OB[(cf*4 + r)*64 + lane]*cB;
    }
    #pragma unroll
    for (int cf = 0; cf < 8; ++cf)
      #pragma unroll
      for (int r = 0; r < 4; ++r)
        Os[(cf*16 + m)*66 + wid*16 + hi*4 + r] = oacc[cf][r] * inv[r];
  }
  __syncthreads();

  // add prior M (rows+cols+diag), then emit M^T bf16 swizzled
  for (int it = 0; it < 16; ++it) {
    int flat = it*512 + tid;
    int c = flat >> 6, qq = flat & 63;
    Os[c*66 + qq] += M[(size_t)c*N_ + q0 + qq];
  }
  __syncthreads();
  #pragma unroll
  for (int e = 0; e < 2; ++e) {
    int u = tid + 512*e;                 // 1024 units: 64 rows x 16 granules
    int nn = u >> 4, gb = u & 15;
    short8 v;
    #pragma unroll
    for (int j = 0; j < 8; ++j) v[j] = f2bf(Os[(gb*8 + j)*66 + nn]);
    int pos = (gb & 8) | ((gb ^ (nn & 7)) & 7);
    *(short8*)(Mtb + (size_t)(q0 + nn)*D_ + pos*8) = v;
  }
}

// ---------------------------------------------------------------------------
extern "C" void kernel_launch(void* const* d_in, const int* in_sizes, int n_in,
                              void* d_out, int out_size, void* d_ws, size_t ws_size,
                              hipStream_t stream) {
  (void)in_sizes; (void)n_in; (void)out_size; (void)ws_size;
  const float* ll  = (const float*)d_in[0];
  const float* hf  = (const float*)d_in[1];
  const float* Wqh = (const float*)d_in[2];
  const float* Wkh = (const float*)d_in[3];
  const float* Wvh = (const float*)d_in[4];
  const float* Wql = (const float*)d_in[5];
  const float* Wkl = (const float*)d_in[6];
  const float* Wvl = (const float*)d_in[7];
  const float* Wph = (const float*)d_in[8];
  const float* bph = (const float*)d_in[9];
  const float* Wpl = (const float*)d_in[10];
  const float* bpl = (const float*)d_in[11];
  const float* Wah = (const float*)d_in[12];
  const float* bah = (const float*)d_in[13];
  const float* Wal = (const float*)d_in[14];
  const float* bal = (const float*)d_in[15];
  const float* alpha = (const float*)d_in[16];

  // workspace layout
  float* ws = (float*)d_ws;
  const size_t BDN = (size_t)B_ * D_ * N_;        // 1M elems
  float* ML = ws;
  float* MH = ML + BDN;
  short* sp = (short*)(MH + BDN);
  short* Qhb = sp;           sp += BDN;
  short* Qlb = sp;           sp += BDN;
  short* Khb = sp;           sp += BDN;
  short* Klb = sp;           sp += BDN;
  short* Vhb = sp;           sp += BDN;
  short* Vlb = sp;           sp += BDN;
  short* Qht = sp;           sp += BDN;
  short* Qlt = sp;           sp += BDN;
  short* Kht = sp;           sp += BDN;
  short* Klt = sp;           sp += BDN;
  short* Vht = sp;           sp += BDN;
  short* Vlt = sp;           sp += BDN;
  short* hfT = sp;           sp += (size_t)B_ * N_ * CH_;
  short* llT = sp;           sp += (size_t)B_ * N_ * CL_;
  short* Mtbl = sp;          sp += BDN;
  short* Mtbh = sp;          sp += BDN;
  short* Utl = sp;           sp += (size_t)B_ * N_ * CL_;
  short* Uth = sp;           sp += (size_t)B_ * N_ * CH_;

  dim3 blk(256, 1, 1);
  const float qscale = (float)(0.08838834764831845 * 1.4426950408889634);
  float* out = (float*)d_out;

  // 1) transpose+convert inputs to bf16 [n][C]
  xt_kernel<<<dim3(N_/64, B_), blk, 0, stream>>>(hf, hfT, CH_);
  xt_kernel<<<dim3(N_/64, B_), blk, 0, stream>>>(ll, llT, CL_);

  // 2) fused QKV MFMA GEMMs (emit Qb/Kb/Vb + Qt/Kt)
  {
    GemmP qh{Wqh, Wkh, Wvh, hfT, nullptr, nullptr, nullptr,
             Qhb, Khb, Vhb, Qht, Kht, nullptr, CH_, D_, 0, qscale};
    gemm_bf16<<<dim3(N_/64, 6, B_), blk, 0, stream>>>(qh);
    GemmP ql{Wql, Wkl, Wvl, llT, nullptr, nullptr, nullptr,
             Qlb, Klb, Vlb, Qlt, Klt, nullptr, CL_, D_, 0, qscale};
    gemm_bf16<<<dim3(N_/64, 6, B_), blk, 0, stream>>>(ql);
  }

  // 3) image-transposed V copies for cols attention
  vt_kernel<<<dim3(64, 2), blk, 0, stream>>>(Vhb, Vlb, Vht, Vlt);

  // 4) axial + diag MFMA attention (rows stores M; cols/diag add)
  {
    SmParams rows{Qhb, Qlb, Khb, Klb, Vhb, Vlb, ML, MH, alpha, 64, 64, 0, 0, 0};
    attn_sm<<<dim3(1, 64, 2*B_), blk, 0, stream>>>(rows);
    SmParams cols{Qht, Qlt, Kht, Klt, Vht, Vlt, ML, MH, alpha, 64, 64, 1, 2, 0};
    attn_sm<<<dim3(1, 64, 2*B_), blk, 0, stream>>>(cols);
    SmParams diag{Qhb, Qlb, Khb, Klb, Vhb, Vlb, ML, MH, alpha, 127, 127, 2, 1, 1};
    attn_sm<<<dim3(2, 1, 2*B_), blk, 0, stream>>>(diag);
  }

  // 5) global attention (adds M, emits M^T bf16)
  GlobalAttnParams gp{Qhb, Qlb, Khb, Klb, Vhb, Vlb, ML, MH, Mtbl, Mtbh, alpha};
  attn_gl_kernel<<<dim3(256, 1, 1), dim3(512,1,1), 0, stream>>>(gp);

  // 6) U = x + Wp @ M + bp  (emit U^T bf16)
  {
    GemmP wpl{Wpl, nullptr, nullptr, Mtbl, ll, bpl, nullptr,
              nullptr, nullptr, nullptr, nullptr, nullptr, Utl, D_, CL_, 1, 1.f};
    gemm_bf16<<<dim3(N_/64, CL_/64, B_), blk, 0, stream>>>(wpl);
    GemmP wph{Wph, nullptr, nullptr, Mtbh, hf, bph, nullptr,
              nullptr, nullptr, nullptr, nullptr, nullptr, Uth, D_, CH_, 1, 1.f};
    gemm_bf16<<<dim3(N_/64, CH_/64, B_), blk, 0, stream>>>(wph);
  }

  // 7) out = Wa @ U + ba
  {
    GemmP wal{Wal, nullptr, nullptr, Utl, nullptr, bal, out,
              nullptr, nullptr, nullptr, nullptr, nullptr, nullptr, CL_, CL_, 2, 1.f};
    gemm_bf16<<<dim3(N_/64, CL_/64, B_), blk, 0, stream>>>(wal);
    GemmP wah{Wah, nullptr, nullptr, Uth, nullptr, bah, out + (size_t)B_*CL_*N_,
              nullptr, nullptr, nullptr, nullptr, nullptr, nullptr, CH_, CH_, 2, 1.f};
    gemm_bf16<<<dim3(N_/64, CH_/64, B_), blk, 0, stream>>>(wah);
  }
}

// Round 7
// 186.089 us; speedup vs baseline: 9.0481x; 1.0342x over previous
//
#include <hip/hip_runtime.h>
#include <math.h>

#define N_  4096
#define D_  128
#define B_  2
#define CL_ 64
#define CH_ 192

typedef __attribute__((ext_vector_type(8))) short short8;
typedef __attribute__((ext_vector_type(4))) float f32x4;
typedef __attribute__((ext_vector_type(16))) float f32x16;

#if __has_builtin(__builtin_amdgcn_exp2f)
#define EXP2(x) __builtin_amdgcn_exp2f(x)
#else
#define EXP2(x) exp2f(x)
#endif

__device__ __forceinline__ short f2bf(float x) {
  union { float f; unsigned u; } v; v.f = x;
  unsigned r = v.u + 0x7FFFu + ((v.u >> 16) & 1u);
  return (short)(r >> 16);
}

typedef __attribute__((address_space(1))) const void gv_t;
typedef __attribute__((address_space(3))) void sv_t;
__device__ __forceinline__ void gl_lds16(const void* g, void* l) {
  __builtin_amdgcn_global_load_lds((gv_t*)g, (sv_t*)l, 16, 0, 0);
}

#define CVTPK(d, lo, hi) asm("v_cvt_pk_bf16_f32 %0, %1, %2" : "=v"(d) : "v"(lo), "v"(hi))
#define PLSWAP(a, b) asm("v_permlane32_swap_b32 %0, %1" : "+v"(a), "+v"(b))

// ---------------------------------------------------------------------------
// XT: f32 [C][4096] -> bf16 [n][C], granule (8 elems) pre-swizzled ^(n&7)
// within each 8-granule (64-elem) window.
// ---------------------------------------------------------------------------
__global__ __launch_bounds__(256)
void xt_kernel(const float* __restrict__ src, short* __restrict__ dst, int C) {
  __shared__ float Ls[CH_][65];
  const int tid = threadIdx.x;
  const int n0 = blockIdx.x * 64;
  const int b = blockIdx.y;
  src += (size_t)b * C * N_;
  dst += (size_t)b * N_ * C;
  for (int flat = tid; flat < C * 64; flat += 256) {
    int c = flat >> 6, nn = flat & 63;
    Ls[c][nn] = src[(size_t)c * N_ + n0 + nn];
  }
  __syncthreads();
  const int ng = C >> 3;
  for (int u = tid; u < 64 * ng; u += 256) {
    int nn = u / ng, g = u - nn * ng;
    short8 v;
    #pragma unroll
    for (int j = 0; j < 8; ++j) v[j] = f2bf(Ls[g*8 + j][nn]);
    int pos = (g & ~7) | ((g ^ (nn & 7)) & 7);
    *(short8*)(dst + (size_t)(n0 + nn) * C + pos * 8) = v;
  }
}

// ---------------------------------------------------------------------------
// Vt: Vb bf16 [d][n] -> image-transposed Vt [d][n'] (n' = w*64+h), same swizzle.
// ---------------------------------------------------------------------------
__global__ __launch_bounds__(256)
void vt_kernel(const short* __restrict__ Vhb, const short* __restrict__ Vlb,
               short* __restrict__ Vht, short* __restrict__ Vlt) {
  __shared__ short rowbuf[4 * 4096];
  const int tid = threadIdx.x;
  const int lane = tid & 63, w = tid >> 6;
  const short* src = blockIdx.y ? Vlb : Vhb;
  short* dst = blockIdx.y ? Vlt : Vht;
  const int r0 = blockIdx.x * 4;
  #pragma unroll
  for (int i = 0; i < 8; ++i) {
    int idx = i * 256 + w * 64 + lane;
    int row = idx >> 9, g = idx & 511;
    gl_lds16(src + (size_t)(r0 + row) * N_ + g * 8,
             (char*)rowbuf + i * 4096 + w * 1024 + lane * 16);
  }
  __syncthreads();
  const int rw = r0 + w, d7 = rw & 7;
  const short* rb = rowbuf + w * 4096;
  const int w0 = (lane & 7) * 8, h0 = (lane >> 3) * 8;
  short8 rr[8];
  #pragma unroll
  for (int j = 0; j < 8; ++j)
    rr[j] = *(const short8*)(rb + (h0 + j) * 64 + (((w0 >> 3) ^ d7) * 8));
  #pragma unroll
  for (int i = 0; i < 8; ++i) {
    short8 o;
    #pragma unroll
    for (int j = 0; j < 8; ++j) o[j] = rr[j][i];
    *(short8*)(dst + (size_t)rw * N_ + (w0 + i) * 64 + (((h0 >> 3) ^ d7) * 8)) = o;
  }
}

// ---------------------------------------------------------------------------
// Unified bf16 MFMA GEMM (unchanged from round 6).
// ---------------------------------------------------------------------------
struct GemmP {
  const float *W0, *W1, *W2;
  const short *Bsrc;
  const float *res, *bias;
  float *outF;
  short *Qb, *Kb, *Vb, *Qt, *Kt;
  short *Ut;
  int K, O, epmode;
  float qscale;
};

__global__ __launch_bounds__(256, 4)
void gemm_bf16(GemmP g) {
  __shared__ __align__(16) char AB[16384];
  __shared__ float Epi[64][67];
  const int tid = threadIdx.x;
  const int lane = tid & 63, w = tid >> 6, m = lane & 15, hi = lane >> 4;
  const int n0 = blockIdx.x * 64;
  const int b = blockIdx.z;
  int sel = 0, dhalf = 0, ot0;
  const float* Wm;
  if (g.epmode == 0) {
    sel = blockIdx.y >> 1; dhalf = blockIdx.y & 1; ot0 = dhalf * 64;
    Wm = sel == 0 ? g.W0 : sel == 1 ? g.W1 : g.W2;
  } else {
    ot0 = blockIdx.y * 64; Wm = g.W0;
  }
  const short* Bs = g.Bsrc + (size_t)b * N_ * g.K;

  f32x4 acc[4];
  #pragma unroll
  for (int i = 0; i < 4; ++i) acc[i] = (f32x4){0.f, 0.f, 0.f, 0.f};

  for (int c0 = 0; c0 < g.K; c0 += 64) {
    __syncthreads();
    {
      int o = tid >> 2, cq = tid & 3;
      const float* wp = Wm + (size_t)(ot0 + o) * g.K + c0 + cq * 16;
      float4 fa = *(const float4*)(wp + 0);
      float4 fb = *(const float4*)(wp + 4);
      float4 fc = *(const float4*)(wp + 8);
      float4 fd = *(const float4*)(wp + 12);
      short8 v0 = { f2bf(fa.x), f2bf(fa.y), f2bf(fa.z), f2bf(fa.w),
                    f2bf(fb.x), f2bf(fb.y), f2bf(fb.z), f2bf(fb.w) };
      short8 v1 = { f2bf(fc.x), f2bf(fc.y), f2bf(fc.z), f2bf(fc.w),
                    f2bf(fd.x), f2bf(fd.y), f2bf(fd.z), f2bf(fd.w) };
      int g0 = cq * 2;
      *(short8*)(AB + o * 128 + (((g0) ^ (o & 7)) * 16)) = v0;
      *(short8*)(AB + o * 128 + (((g0 + 1) ^ (o & 7)) * 16)) = v1;
    }
    #pragma unroll
    for (int e = 0; e < 2; ++e) {
      int cid = e * 256 + w * 64 + lane;
      int nn = cid >> 3, gs = cid & 7;
      gl_lds16(Bs + (size_t)(n0 + nn) * g.K + c0 + gs * 8,
               AB + 8192 + e * 4096 + w * 1024 + lane * 16);
    }
    __syncthreads();
    const int orow = w * 16 + m;
    short8 a0 = *(const short8*)(AB + orow * 128 + (((hi) ^ (orow & 7)) * 16));
    short8 a1 = *(const short8*)(AB + orow * 128 + (((4 + hi) ^ (orow & 7)) * 16));
    #pragma unroll
    for (int nf = 0; nf < 4; ++nf) {
      int nrow = nf * 16 + m;
      short8 b0 = *(const short8*)(AB + 8192 + nrow * 128 + (((hi) ^ (nrow & 7)) * 16));
      short8 b1 = *(const short8*)(AB + 8192 + nrow * 128 + (((4 + hi) ^ (nrow & 7)) * 16));
      acc[nf] = __builtin_amdgcn_mfma_f32_16x16x32_bf16(a0, b0, acc[nf], 0, 0, 0);
      acc[nf] = __builtin_amdgcn_mfma_f32_16x16x32_bf16(a1, b1, acc[nf], 0, 0, 0);
    }
  }

  #pragma unroll
  for (int nf = 0; nf < 4; ++nf)
    #pragma unroll
    for (int r = 0; r < 4; ++r)
      Epi[w * 16 + hi * 4 + r][nf * 16 + m] = acc[nf][r];
  __syncthreads();

  if (g.epmode == 0) {
    if (sel < 2) {
      float sc = (sel == 0) ? g.qscale : 1.f;
      short* QK = (sel == 0 ? g.Qb : g.Kb) + (size_t)b * N_ * D_;
      short* QKt = (sel == 0 ? g.Qt : g.Kt) + (size_t)b * N_ * D_;
      const int bx = blockIdx.x;
      #pragma unroll
      for (int e = 0; e < 2; ++e) {
        int u = tid + 256 * e;
        int nn = u >> 3, gl = u & 7;
        short8 v;
        #pragma unroll
        for (int j = 0; j < 8; ++j) v[j] = f2bf(Epi[gl*8 + j][nn] * sc);
        int posb = (dhalf * 8) | ((gl ^ (nn & 7)) & 7);
        *(short8*)(QK + (size_t)(n0 + nn) * D_ + posb * 8) = v;
        int post = (dhalf * 8) | ((gl ^ (bx & 7)) & 7);
        *(short8*)(QKt + (size_t)(nn * 64 + bx) * D_ + post * 8) = v;
      }
    } else {
      short* Vb = g.Vb + (size_t)b * D_ * N_;
      #pragma unroll
      for (int e = 0; e < 2; ++e) {
        int u = tid + 256 * e;
        int o = u >> 3, gl = u & 7;
        int d = ot0 + o;
        short8 v;
        #pragma unroll
        for (int j = 0; j < 8; ++j) v[j] = f2bf(Epi[o][gl*8 + j]);
        *(short8*)(Vb + (size_t)d * N_ + n0 + ((gl ^ (d & 7)) * 8)) = v;
      }
    }
  } else if (g.epmode == 1) {
    const float* res = g.res + (size_t)b * g.O * N_;
    short* Ut = g.Ut + (size_t)b * N_ * g.O;
    #pragma unroll
    for (int e = 0; e < 2; ++e) {
      int nn = tid & 63;
      int gl = (tid >> 6) + e * 4;
      int ob = ot0 + gl * 8;
      short8 v;
      #pragma unroll
      for (int j = 0; j < 8; ++j)
        v[j] = f2bf(Epi[gl*8 + j][nn] + res[(size_t)(ob + j) * N_ + n0 + nn] + g.bias[ob + j]);
      int gout = (ot0 >> 3) + gl;
      int pos = (gout & ~7) | ((gout ^ (nn & 7)) & 7);
      *(short8*)(Ut + (size_t)(n0 + nn) * g.O + pos * 8) = v;
    }
  } else {
    int o = tid >> 2, nq = tid & 3;
    float bv = g.bias[ot0 + o];
    float* dst = g.outF + (size_t)b * g.O * N_ + (size_t)(ot0 + o) * N_ + n0 + nq * 16;
    #pragma unroll
    for (int q4 = 0; q4 < 4; ++q4) {
      float4 vv = { Epi[o][nq*16 + q4*4 + 0] + bv, Epi[o][nq*16 + q4*4 + 1] + bv,
                    Epi[o][nq*16 + q4*4 + 2] + bv, Epi[o][nq*16 + q4*4 + 3] + bv };
      *(float4*)(dst + q4 * 4) = vv;
    }
  }
}

// ---------------------------------------------------------------------------
// Small MFMA flash attention (rows / cols / diag) — unchanged from round 6.
// ---------------------------------------------------------------------------
struct SmParams {
  const short *Qh, *Ql, *Kh, *Kl, *Vh, *Vl;
  float *ML, *MH;
  const float* alpha;
  int Lq, Lk, widx, outmode, cwflag;
};

__global__ __launch_bounds__(256, 2)
void attn_sm(SmParams p) {
  __shared__ __align__(16) char smem[49152];
  const int tid = threadIdx.x;
  const int lane = tid & 63, w = tid >> 6, m = lane & 15, hi = lane >> 4;
  const int bz = blockIdx.z, b = bz >> 1, pair = bz & 1;
  const int y = blockIdx.y, bx = blockIdx.x;
  const int qbase = bx * 64 + y * 64;
  const int kcol0 = y * 64;

  const short* Qs = (pair ? p.Ql : p.Qh) + (size_t)b * N_ * D_;
  const short* Ks = (pair ? p.Kh : p.Kl) + (size_t)b * N_ * D_;
  const short* Vs = (pair ? p.Vh : p.Vl) + (size_t)b * D_ * N_;
  float* M = (pair ? p.MH : p.ML) + (size_t)b * D_ * N_;

  float a0 = p.alpha[0], a1 = p.alpha[1], a2 = p.alpha[2], a3 = p.alpha[3];
  float am = fmaxf(fmaxf(a0, a1), fmaxf(a2, a3));
  float e0 = __expf(a0-am), e1 = __expf(a1-am), e2 = __expf(a2-am), e3 = __expf(a3-am);
  float wsel = (p.widx == 0 ? e0 : p.widx == 1 ? e1 : e2) / (e0 + e1 + e2 + e3);

  int lqloc = p.Lq - bx * 64; if (lqloc > 64) lqloc = 64;

  auto stageK = [&](int kt) {
    #pragma unroll
    for (int i = 0; i < 4; ++i) {
      int chunk = w * 4 + i;
      gl_lds16(Ks + (size_t)(kcol0 + kt*64) * D_ + chunk * 512 + lane * 8,
               smem + 16384 + chunk * 1024);
    }
  };
  auto stageV = [&](int kt) {
    #pragma unroll
    for (int i = 0; i < 4; ++i) {
      int chunk = w * 4 + i;
      gl_lds16(Vs + (size_t)(chunk*8 + (lane>>3)) * N_ + kcol0 + kt*64 + (lane&7)*8,
               smem + 32768 + chunk * 1024);
    }
  };
  #pragma unroll
  for (int i = 0; i < 4; ++i) {
    int chunk = w * 4 + i;
    gl_lds16(Qs + (size_t)qbase * D_ + chunk * 512 + lane * 8, smem + chunk * 1024);
  }
  stageK(0); stageV(0);
  __syncthreads();

  const int qrow = w * 16 + m;
  short8 qf[4];
  #pragma unroll
  for (int cs = 0; cs < 4; ++cs)
    qf[cs] = *(const short8*)(smem + qrow * 256 + ((cs*64 + hi*16) ^ ((qrow & 7) << 4)));
  __syncthreads();

  f32x4 oacc[8];
  #pragma unroll
  for (int i = 0; i < 8; ++i) oacc[i] = (f32x4){0.f, 0.f, 0.f, 0.f};
  float m_run[4] = {-INFINITY, -INFINITY, -INFINITY, -INFINITY};
  float l_run[4] = {0.f, 0.f, 0.f, 0.f};
  char* const pstrip = smem + w * 2048;
  const int NT = (p.Lk + 63) >> 6;

  for (int kt = 0; kt < NT; ++kt) {
    const char* Kc = smem + 16384;
    const char* Vc = smem + 32768;
    f32x4 sacc[4];
    #pragma unroll
    for (int kf = 0; kf < 4; ++kf) sacc[kf] = (f32x4){0.f, 0.f, 0.f, 0.f};
    #pragma unroll
    for (int kf = 0; kf < 4; ++kf) {
      const int krow = kf * 16 + m;
      const char* kr = Kc + krow * 256;
      #pragma unroll
      for (int cs = 0; cs < 4; ++cs) {
        short8 kfr = *(const short8*)(kr + ((cs*64 + hi*16) ^ ((krow & 7) << 4)));
        sacc[kf] = __builtin_amdgcn_mfma_f32_16x16x32_bf16(qf[cs], kfr, sacc[kf], 0, 0, 0);
      }
    }
    float cw[4];
    #pragma unroll
    for (int kf = 0; kf < 4; ++kf) {
      if (p.cwflag) {
        int kg = kt * 64 + kf * 16 + m;
        int dd = kg - 63; dd = dd < 0 ? -dd : dd;
        cw[kf] = (kg < p.Lk) ? (float)(64 - dd) : 0.f;
      } else cw[kf] = 1.f;
    }
    #pragma unroll
    for (int r = 0; r < 4; ++r) {
      float mt = fmaxf(fmaxf(sacc[0][r], sacc[1][r]), fmaxf(sacc[2][r], sacc[3][r]));
      mt = fmaxf(mt, __shfl_xor(mt, 1));
      mt = fmaxf(mt, __shfl_xor(mt, 2));
      mt = fmaxf(mt, __shfl_xor(mt, 4));
      mt = fmaxf(mt, __shfl_xor(mt, 8));
      float mn = fmaxf(m_run[r], mt);
      float corr = EXP2(m_run[r] - mn);
      m_run[r] = mn;
      const int rl = hi * 4 + r;
      char* prow = pstrip + rl * 128;
      float psum = 0.f;
      #pragma unroll
      for (int kf = 0; kf < 4; ++kf) {
        float pv = cw[kf] * EXP2(sacc[kf][r] - mn);
        psum += pv;
        int kcol = (kf * 16 + m) * 2;
        *(short*)(prow + (kcol ^ ((rl & 7) << 4))) = f2bf(pv);
      }
      psum += __shfl_xor(psum, 1);
      psum += __shfl_xor(psum, 2);
      psum += __shfl_xor(psum, 4);
      psum += __shfl_xor(psum, 8);
      l_run[r] = l_run[r] * corr + psum;
      #pragma unroll
      for (int cf = 0; cf < 8; ++cf) oacc[cf][r] *= corr;
    }
    #pragma unroll
    for (int ks = 0; ks < 2; ++ks) {
      short8 pa = *(const short8*)(pstrip + m * 128 + ((ks*64 + hi*16) ^ ((m & 7) << 4)));
      #pragma unroll
      for (int cf = 0; cf < 8; ++cf) {
        const int crow = cf * 16 + m;
        short8 vf = *(const short8*)(Vc + crow * 128 + ((ks*64 + hi*16) ^ ((crow & 7) << 4)));
        oacc[cf] = __builtin_amdgcn_mfma_f32_16x16x32_bf16(pa, vf, oacc[cf], 0, 0, 0);
      }
    }
    __syncthreads();
    if (kt + 1 < NT) { stageK(kt + 1); stageV(kt + 1); __syncthreads(); }
  }

  float inv[4];
  #pragma unroll
  for (int r = 0; r < 4; ++r) inv[r] = wsel / l_run[r];
  float* Os = (float*)smem;
  #pragma unroll
  for (int cf = 0; cf < 8; ++cf)
    #pragma unroll
    for (int r = 0; r < 4; ++r)
      Os[(cf*16 + m) * 66 + w * 16 + hi * 4 + r] = oacc[cf][r] * inv[r];
  __syncthreads();
  for (int it = 0; it < 32; ++it) {
    int flat = it * 256 + tid;
    int c = flat >> 6, qq = flat & 63;
    if (qq < lqloc) {
      float v = Os[c * 66 + qq];
      if (p.outmode == 0)      M[(size_t)c * N_ + qbase + qq] = v;
      else if (p.outmode == 1) M[(size_t)c * N_ + qbase + qq] += v;
      else                     M[(size_t)c * N_ + qq * 64 + y] += v;
    }
  }
}

// ---------------------------------------------------------------------------
// Global attention v2: 256 blocks x 256 thr (4 waves = 2 q-strips x 2 parity).
// 32x32x16 MFMA, swapped operands: S^T = mfma(K, Q) -> lane owns query
// (col = lane&31, m89/m74 C/D layout); softmax fully in-register
// (permlane32_swap for cross-half); P -> PV B-operand via cvt_pk + swaps (T12);
// O^T = mfma(V, P), per-lane scalar rescale + defer-max (T13).
// KVBLK=32, quad K slots + dual V pair-buffers, distance-1 prefetch issued
// AFTER the per-iter __syncthreads (race-free slot reuse). 80KB LDS -> 2 blk/CU.
// Runs LAST: adds prior M (rows+cols+diag), emits M^T bf16 for Wp GEMM.
// ---------------------------------------------------------------------------
#define KOFF 16384
#define VOFF 49152

struct GlobalAttnParams {
  const short *Qhb, *Qlb, *Khb, *Klb, *Vhb, *Vlb;
  float *ML, *MH;
  short *Mtbl, *Mtbh;
  const float* alpha;
};

__global__ __launch_bounds__(256, 2)
void attn_gl_kernel(GlobalAttnParams p) {
  __shared__ __align__(16) char smem[81920];
  const int tid = threadIdx.x;
  const int lane = tid & 63, w = tid >> 6;     // 4 waves
  const int wid = w & 1, gsel = w >> 1;        // q-strip, tile parity
  const int key = lane & 31, kh = lane >> 5;   // row-in-frag, k-half

  const int bx = blockIdx.x;
  const int xcd = bx & 7, sub = bx >> 3;       // sub 0..31
  const int pz = xcd >> 1;
  const int b = pz >> 1, pair = pz & 1;
  const int q0 = ((xcd & 1) * 32 + sub) * 64;

  const short* Qb = (pair ? p.Qlb : p.Qhb) + (size_t)b * N_ * D_;
  const short* Kb = (pair ? p.Khb : p.Klb) + (size_t)b * N_ * D_;
  const short* Vb = (pair ? p.Vhb : p.Vlb) + (size_t)b * D_ * N_;
  float* M = (pair ? p.MH : p.ML) + (size_t)b * D_ * N_;
  short* Mtb = (pair ? p.Mtbh : p.Mtbl) + (size_t)b * N_ * D_;

  float a0 = p.alpha[0], a1 = p.alpha[1], a2 = p.alpha[2], a3 = p.alpha[3];
  float am = fmaxf(fmaxf(a0,a1), fmaxf(a2,a3));
  float e0 = __expf(a0-am), e1 = __expf(a1-am), e2 = __expf(a2-am), e3 = __expf(a3-am);
  const float wsel = e3 / (e0+e1+e2+e3);

  // stage pair pp: K tiles {2pp, 2pp+1} -> slots (t&3); V 64-key pair buf (pp&1)
  auto stagePair = [&](int pp) {
    #pragma unroll
    for (int i = 0; i < 8; ++i) {
      int c = w*8 + i;                       // 0..31
      if (c < 16) {
        int tk = 2*pp + (c >> 3), ck = c & 7;
        gl_lds16(Kb + (size_t)(tk*32 + ck*4)*D_ + lane*8,
                 smem + KOFF + (tk & 3)*8192 + ck*1024);
      } else {
        int cc = c - 16;
        gl_lds16(Vb + (size_t)(cc*8 + (lane>>3))*N_ + pp*64 + (lane&7)*8,
                 smem + VOFF + (pp & 1)*16384 + cc*1024);
      }
    }
  };

  // prologue: Q (16KB, 4 chunks/wave) + pair 0
  #pragma unroll
  for (int i = 0; i < 4; ++i) {
    int chunk = w*4 + i;
    gl_lds16(Qb + (size_t)q0*D_ + chunk*512 + lane*8, smem + chunk*1024);
  }
  stagePair(0);
  __syncthreads();

  // hoist Q (B-operand: row = lane&31 = query, k = kh*8+j)
  const int qq = wid*32 + key;
  short8 qf[8];
  #pragma unroll
  for (int fi = 0; fi < 8; ++fi)
    qf[fi] = *(const short8*)(smem + qq*256 + (((fi*2 + kh) ^ (qq & 7)) << 4));

  f32x16 oacc[4];
  #pragma unroll
  for (int d = 0; d < 4; ++d)
    #pragma unroll
    for (int r = 0; r < 16; ++r) oacc[d][r] = 0.f;
  float m_run = -INFINITY, l_run = 0.f;

  const int NP = N_ / 64;                    // 64 pairs of 32-key tiles
  for (int j = 0; j < NP; ++j) {
    __syncthreads();                         // drains vmcnt(0): pair j committed
    if (j + 1 < NP) stagePair(j + 1);        // disjoint slots from pair j

    const int t = 2*j + gsel;
    const char* Kc = smem + KOFF + (t & 3)*8192;
    const char* Vc = smem + VOFF + (j & 1)*16384;

    // ---- S^T = mfma(K, Q): lane owns query qq, 32 key-scores in 16 regs ----
    f32x16 sacc;
    #pragma unroll
    for (int r = 0; r < 16; ++r) sacc[r] = 0.f;
    __builtin_amdgcn_s_setprio(1);
    #pragma unroll
    for (int fi = 0; fi < 8; ++fi) {
      short8 kf = *(const short8*)(Kc + key*256 + (((fi*2 + kh) ^ (key & 7)) << 4));
      sacc = __builtin_amdgcn_mfma_f32_32x32x16_bf16(kf, qf[fi], sacc, 0, 0, 0);
    }
    __builtin_amdgcn_s_setprio(0);

    // ---- in-register online softmax (log2 domain; scl*log2e folded in Q) ----
    float mt = sacc[0];
    #pragma unroll
    for (int r = 1; r < 16; ++r) mt = fmaxf(mt, sacc[r]);
    { float aa = mt, bb = mt; PLSWAP(aa, bb); mt = fmaxf(aa, bb); }
    if (!__all(mt <= m_run + 8.f)) {         // defer-max (T13)
      float mn = fmaxf(m_run, mt);
      float corr = EXP2(m_run - mn);
      m_run = mn;
      l_run *= corr;
      #pragma unroll
      for (int d = 0; d < 4; ++d)
        #pragma unroll
        for (int r = 0; r < 16; ++r) oacc[d][r] *= corr;
    }
    float pv[16];
    float psum = 0.f;
    #pragma unroll
    for (int r = 0; r < 16; ++r) { pv[r] = EXP2(sacc[r] - m_run); psum += pv[r]; }
    { float sa = psum, sb = psum; PLSWAP(sa, sb); psum = sa + sb; }
    l_run += psum;

    // ---- P -> bf16 B-operand frags (cvt_pk + permlane32_swap, T12) ----
    union U8 { unsigned u[4]; short8 s; } pf0, pf1;
    {
      unsigned c0, c1, c2, c3;
      CVTPK(c0, pv[0], pv[1]);  CVTPK(c1, pv[2], pv[3]);
      CVTPK(c2, pv[4], pv[5]);  CVTPK(c3, pv[6], pv[7]);
      PLSWAP(c0, c2); PLSWAP(c1, c3);
      pf0.u[0] = c0; pf0.u[1] = c1; pf0.u[2] = c2; pf0.u[3] = c3;
      CVTPK(c0, pv[8],  pv[9]);  CVTPK(c1, pv[10], pv[11]);
      CVTPK(c2, pv[12], pv[13]); CVTPK(c3, pv[14], pv[15]);
      PLSWAP(c0, c2); PLSWAP(c1, c3);
      pf1.u[0] = c0; pf1.u[1] = c1; pf1.u[2] = c2; pf1.u[3] = c3;
    }

    // ---- O^T += mfma(V, P): col = query, rows = d ----
    __builtin_amdgcn_s_setprio(1);
    #pragma unroll
    for (int d = 0; d < 4; ++d) {
      #pragma unroll
      for (int ks = 0; ks < 2; ++ks) {
        int gg = gsel*4 + ks*2 + kh;
        short8 vf = *(const short8*)(Vc + (d*32 + key)*128 + ((gg ^ (key & 7)) << 4));
        oacc[d] = __builtin_amdgcn_mfma_f32_32x32x16_bf16(vf, (ks ? pf1.s : pf0.s), oacc[d], 0, 0, 0);
      }
    }
    __builtin_amdgcn_s_setprio(0);
  }
  __syncthreads();

  // ---- parity merge: gsel=1 -> LDS, gsel=0 combines (per-lane scalars) ----
  float* MLp = (float*)(smem + 34816);
  float* OBp = (float*)(smem + VOFF);
  if (gsel == 1) {
    float* ob = OBp + wid*4096;
    #pragma unroll
    for (int d = 0; d < 4; ++d)
      #pragma unroll
      for (int r = 0; r < 16; ++r)
        ob[(d*16 + r)*64 + lane] = oacc[d][r];
    float* ml = MLp + wid*128;
    ml[lane] = m_run; ml[64 + lane] = l_run;
  }
  __syncthreads();

  float* Os = (float*)smem;                  // [128][66] f32 at offset 0
  if (gsel == 0) {
    const float* ob = OBp + wid*4096;
    const float* ml = MLp + wid*128;
    float mB = ml[lane], lB = ml[64 + lane];
    float mn = fmaxf(m_run, mB);
    float cA = EXP2(m_run - mn), cB = EXP2(mB - mn);
    float inv = wsel / (l_run*cA + lB*cB);
    #pragma unroll
    for (int d = 0; d < 4; ++d)
      #pragma unroll
      for (int r = 0; r < 16; ++r) {
        float o = oacc[d][r]*cA + ob[(d*16 + r)*64 + lane]*cB;
        int dr = d*32 + (r & 3) + 8*(r >> 2) + 4*kh;
        Os[dr*66 + qq] = o * inv;
      }
  }
  __syncthreads();

  // add prior M (rows+cols+diag), then emit M^T bf16 swizzled
  for (int it = 0; it < 32; ++it) {
    int flat = it*256 + tid;
    int c = flat >> 6, q2 = flat & 63;
    Os[c*66 + q2] += M[(size_t)c*N_ + q0 + q2];
  }
  __syncthreads();
  #pragma unroll
  for (int e = 0; e < 4; ++e) {
    int u = tid + 256*e;                     // 1024 units: 64 rows x 16 granules
    int nn = u >> 4, gb = u & 15;
    short8 v;
    #pragma unroll
    for (int jj = 0; jj < 8; ++jj) v[jj] = f2bf(Os[(gb*8 + jj)*66 + nn]);
    int pos = (gb & 8) | ((gb ^ (nn & 7)) & 7);
    *(short8*)(Mtb + (size_t)(q0 + nn)*D_ + pos*8) = v;
  }
}

// ---------------------------------------------------------------------------
extern "C" void kernel_launch(void* const* d_in, const int* in_sizes, int n_in,
                              void* d_out, int out_size, void* d_ws, size_t ws_size,
                              hipStream_t stream) {
  (void)in_sizes; (void)n_in; (void)out_size; (void)ws_size;
  const float* ll  = (const float*)d_in[0];
  const float* hf  = (const float*)d_in[1];
  const float* Wqh = (const float*)d_in[2];
  const float* Wkh = (const float*)d_in[3];
  const float* Wvh = (const float*)d_in[4];
  const float* Wql = (const float*)d_in[5];
  const float* Wkl = (const float*)d_in[6];
  const float* Wvl = (const float*)d_in[7];
  const float* Wph = (const float*)d_in[8];
  const float* bph = (const float*)d_in[9];
  const float* Wpl = (const float*)d_in[10];
  const float* bpl = (const float*)d_in[11];
  const float* Wah = (const float*)d_in[12];
  const float* bah = (const float*)d_in[13];
  const float* Wal = (const float*)d_in[14];
  const float* bal = (const float*)d_in[15];
  const float* alpha = (const float*)d_in[16];

  float* ws = (float*)d_ws;
  const size_t BDN = (size_t)B_ * D_ * N_;
  float* ML = ws;
  float* MH = ML + BDN;
  short* sp = (short*)(MH + BDN);
  short* Qhb = sp;           sp += BDN;
  short* Qlb = sp;           sp += BDN;
  short* Khb = sp;           sp += BDN;
  short* Klb = sp;           sp += BDN;
  short* Vhb = sp;           sp += BDN;
  short* Vlb = sp;           sp += BDN;
  short* Qht = sp;           sp += BDN;
  short* Qlt = sp;           sp += BDN;
  short* Kht = sp;           sp += BDN;
  short* Klt = sp;           sp += BDN;
  short* Vht = sp;           sp += BDN;
  short* Vlt = sp;           sp += BDN;
  short* hfT = sp;           sp += (size_t)B_ * N_ * CH_;
  short* llT = sp;           sp += (size_t)B_ * N_ * CL_;
  short* Mtbl = sp;          sp += BDN;
  short* Mtbh = sp;          sp += BDN;
  short* Utl = sp;           sp += (size_t)B_ * N_ * CL_;
  short* Uth = sp;           sp += (size_t)B_ * N_ * CH_;

  dim3 blk(256, 1, 1);
  const float qscale = (float)(0.08838834764831845 * 1.4426950408889634);
  float* out = (float*)d_out;

  // 1) transpose+convert inputs to bf16 [n][C]
  xt_kernel<<<dim3(N_/64, B_), blk, 0, stream>>>(hf, hfT, CH_);
  xt_kernel<<<dim3(N_/64, B_), blk, 0, stream>>>(ll, llT, CL_);

  // 2) fused QKV MFMA GEMMs (emit Qb/Kb/Vb + Qt/Kt)
  {
    GemmP qh{Wqh, Wkh, Wvh, hfT, nullptr, nullptr, nullptr,
             Qhb, Khb, Vhb, Qht, Kht, nullptr, CH_, D_, 0, qscale};
    gemm_bf16<<<dim3(N_/64, 6, B_), blk, 0, stream>>>(qh);
    GemmP ql{Wql, Wkl, Wvl, llT, nullptr, nullptr, nullptr,
             Qlb, Klb, Vlb, Qlt, Klt, nullptr, CL_, D_, 0, qscale};
    gemm_bf16<<<dim3(N_/64, 6, B_), blk, 0, stream>>>(ql);
  }

  // 3) image-transposed V copies for cols attention
  vt_kernel<<<dim3(64, 2), blk, 0, stream>>>(Vhb, Vlb, Vht, Vlt);

  // 4) axial + diag MFMA attention (rows stores M; cols/diag add)
  {
    SmParams rows{Qhb, Qlb, Khb, Klb, Vhb, Vlb, ML, MH, alpha, 64, 64, 0, 0, 0};
    attn_sm<<<dim3(1, 64, 2*B_), blk, 0, stream>>>(rows);
    SmParams cols{Qht, Qlt, Kht, Klt, Vht, Vlt, ML, MH, alpha, 64, 64, 1, 2, 0};
    attn_sm<<<dim3(1, 64, 2*B_), blk, 0, stream>>>(cols);
    SmParams diag{Qhb, Qlb, Khb, Klb, Vhb, Vlb, ML, MH, alpha, 127, 127, 2, 1, 1};
    attn_sm<<<dim3(2, 1, 2*B_), blk, 0, stream>>>(diag);
  }

  // 5) global attention (adds M, emits M^T bf16)
  GlobalAttnParams gp{Qhb, Qlb, Khb, Klb, Vhb, Vlb, ML, MH, Mtbl, Mtbh, alpha};
  attn_gl_kernel<<<dim3(256, 1, 1), dim3(256,1,1), 0, stream>>>(gp);

  // 6) U = x + Wp @ M + bp  (emit U^T bf16)
  {
    GemmP wpl{Wpl, nullptr, nullptr, Mtbl, ll, bpl, nullptr,
              nullptr, nullptr, nullptr, nullptr, nullptr, Utl, D_, CL_, 1, 1.f};
    gemm_bf16<<<dim3(N_/64, CL_/64, B_), blk, 0, stream>>>(wpl);
    GemmP wph{Wph, nullptr, nullptr, Mtbh, hf, bph, nullptr,
              nullptr, nullptr, nullptr, nullptr, nullptr, Uth, D_, CH_, 1, 1.f};
    gemm_bf16<<<dim3(N_/64, CH_/64, B_), blk, 0, stream>>>(wph);
  }

  // 7) out = Wa @ U + ba
  {
    GemmP wal{Wal, nullptr, nullptr, Utl, nullptr, bal, out,
              nullptr, nullptr, nullptr, nullptr, nullptr, nullptr, CL_, CL_, 2, 1.f};
    gemm_bf16<<<dim3(N_/64, CL_/64, B_), blk, 0, stream>>>(wal);
    GemmP wah{Wah, nullptr, nullptr, Uth, nullptr, bah, out + (size_t)B_*CL_*N_,
              nullptr, nullptr, nullptr, nullptr, nullptr, nullptr, CH_, CH_, 2, 1.f};
    gemm_bf16<<<dim3(N_/64, CH_/64, B_), blk, 0, stream>>>(wah);
  }
}